// Round 12
// baseline (1105.587 us; speedup 1.0000x reference)
//
#include <hip/hip_runtime.h>

// MiniCPM-style decode step: L=8 B=4 H=16 HKV=8 D=64 S=2048 HID=1024 FF=2816
#define L_   8
#define B_   4
#define H_   16
#define HKV_ 8
#define D_   64
#define S_   2048
#define HID_ 1024
#define FF_  2816
#define EPS_ 1e-5f
#define MUP_ 0.49497474683058327f   // 1.4/sqrt(8)
#define SCALE_ 0.125f               // 1/sqrt(64)
#define NCH_ 32                     // attention chunks of 64 positions

// d_out is FLOAT32: [h 4096 | k_upd 16384 | v_upd 16384 | pos+1]
#define OUT_H   0
#define OUT_K   4096
#define OUT_V   (4096 + 16384)
#define OUT_POS (4096 + 16384 + 16384)

// ======== mega-kernel per-layer one-shot buffers (floats), transposed ========
#define PL_QP   0            // 262144 [b][col<2048][kc<32]
#define PL_AM   262144       // 1024   [(b*8+kv)*2+g][ns<32]
#define PL_AL   263168       // 1024
#define PL_AO   264192       // 131072 [b][h<16][d<64][ns<32]
#define PL_HCA  395264       // 4096   [col][b]
#define PL_HCB  399360       // 4096   [col][b]
#define PL_GP   403456       // 360448 [b][col<2816][kc<32]
#define PL_UP   763904       // 360448
#define PL_SZ   1124352
#define FL_BASE (8 * PL_SZ)             // flags (ints) after partials
#define NEED_FLOATS (FL_BASE + 1024)
#define FI(l,k) (((l) * 5 + (k)) * 16)  // k: 0=QP 1=AT 2=OP 3=GU 4=DN

__device__ __forceinline__ int read_pos_dev(const int* p) {
  int v = p[0];
  if (v >= 0 && v < S_) return v;
  float f = __int_as_float(v);
  if (f >= 0.0f && f <= (float)(S_ - 1)) return (int)(f + 0.5f);
  return 1500;
}
__device__ __forceinline__ float wave_sum(float v) {
  for (int m = 1; m < 64; m <<= 1) v += __shfl_xor(v, m);
  return v;
}
__device__ __forceinline__ float wave_max(float v) {
  for (int m = 1; m < 64; m <<= 1) v = fmaxf(v, __shfl_xor(v, m));
  return v;
}
// write-through (agent-coherent) store: fire-and-forget, no fence
__device__ __forceinline__ void stg_a(float* p, float v) {
  __hip_atomic_store(p, v, __ATOMIC_RELAXED, __HIP_MEMORY_SCOPE_AGENT);
}
__device__ __forceinline__ void fwait(int* flg, int idx, int target) {
  if (threadIdx.x == 0) {
    int n = 0;
    while (__hip_atomic_load(flg + idx, __ATOMIC_RELAXED,
                             __HIP_MEMORY_SCOPE_AGENT) < target) {
      __builtin_amdgcn_s_sleep(32);
      if (++n > (1 << 22)) break;
    }
  }
  __syncthreads();
}
// call only AFTER a __syncthreads() (drains block stores)
__device__ __forceinline__ void fadd(int* flg, int idx) {
  if (threadIdx.x == 0) atomicAdd(flg + idx, 1);
}

__global__ void k_init(float* ws) {
  int i = blockIdx.x * 256 + threadIdx.x;
  if (i < 1024) ((int*)(ws + FL_BASE))[i] = 0;
}

// =============================== THE MEGA ===================================
__global__ void __launch_bounds__(256, 2)
mega(const float* __restrict__ kcache, const float* __restrict__ vcache,
     const float* __restrict__ Wq, const float* __restrict__ Wk,
     const float* __restrict__ Wv, const float* __restrict__ Wo,
     const float* __restrict__ Wg, const float* __restrict__ Wu,
     const float* __restrict__ Wd, const float* __restrict__ n1,
     const float* __restrict__ n2, const float* __restrict__ fw,
     const float* __restrict__ x, const int* __restrict__ posp,
     float* ws, float* out) {
  const int bid = blockIdx.x, t = threadIdx.x;
  int* flg = (int*)(ws + FL_BASE);
  const int pos = read_pos_dev(posp);
  __shared__ __align__(16) float smem[9872];

  if (bid == 4 && t == 0) out[OUT_POS] = (float)(pos + 1);

  #pragma unroll 1
  for (int l = 0; l < L_; ++l) {
    float* qp_  = ws + (size_t)l * PL_SZ + PL_QP;
    float* am_  = ws + (size_t)l * PL_SZ + PL_AM;
    float* al_  = ws + (size_t)l * PL_SZ + PL_AL;
    float* ao_  = ws + (size_t)l * PL_SZ + PL_AO;
    float* hca_ = ws + (size_t)l * PL_SZ + PL_HCA;
    float* hcb_ = ws + (size_t)l * PL_SZ + PL_HCB;
    float* gp_  = ws + (size_t)l * PL_SZ + PL_GP;
    float* up_  = ws + (size_t)l * PL_SZ + PL_UP;

    // ================= QKV phase (bid < 256) =================
    if (bid < 256) {
      int cb = bid & 7, kc = bid >> 3;
      int col = cb * 256 + t;
      const float* W; int wcol, stride;
      if (col < 1024)      { W = Wq + (size_t)l * HID_ * 1024; wcol = col;        stride = 1024; }
      else if (col < 1536) { W = Wk + (size_t)l * HID_ * 512;  wcol = col - 1024; stride = 512;  }
      else                 { W = Wv + (size_t)l * HID_ * 512;  wcol = col - 1536; stride = 512;  }
      const float* wp = W + (size_t)(kc * 32) * stride + wcol;
      float wv[32];
      #pragma unroll
      for (int i = 0; i < 32; ++i) wv[i] = wp[(size_t)i * stride];  // hoisted

      if (l > 0) fwait(flg, FI(l - 1, 4), 352);   // wait prev DOWN

      const float* hcbp = ws + (size_t)(l - 1) * PL_SZ + PL_HCB;  // valid for l>0
      float4 h4[4];
      #pragma unroll
      for (int j = 0; j < 4; ++j) {
        int c2 = t + j * 256;
        if (l == 0) h4[j] = make_float4(x[c2], x[1024 + c2], x[2048 + c2], x[3072 + c2]);
        else        h4[j] = *(const float4*)&hcbp[c2 * 4];
      }
      float part[4] = {0.f, 0.f, 0.f, 0.f};
      #pragma unroll
      for (int j = 0; j < 4; ++j) {
        part[0] += h4[j].x * h4[j].x; part[1] += h4[j].y * h4[j].y;
        part[2] += h4[j].z * h4[j].z; part[3] += h4[j].w * h4[j].w;
      }
      float* red = smem;            // 16
      float* xs  = smem + 16;       // 128 [b*32+i]
      int w_ = t >> 6;
      #pragma unroll
      for (int b = 0; b < 4; ++b) {
        float s = wave_sum(part[b]);
        if ((t & 63) == 0) red[w_ * 4 + b] = s;
      }
      __syncthreads();
      float rs[4];
      #pragma unroll
      for (int b = 0; b < 4; ++b)
        rs[b] = rsqrtf((red[b] + red[4 + b] + red[8 + b] + red[12 + b]) * (1.0f / HID_) + EPS_);
      if (bid < 4) {  // seed HCA[l] with h (component bid)
        #pragma unroll
        for (int j = 0; j < 4; ++j) {
          int c2 = t + j * 256;
          float v = (bid == 0) ? h4[j].x : (bid == 1) ? h4[j].y : (bid == 2) ? h4[j].z : h4[j].w;
          stg_a(hca_ + c2 * 4 + bid, v);
        }
      }
      if (t < 128) {
        int b = t >> 5, i = t & 31;
        int gc = kc * 32 + i;
        float hval = (l == 0) ? x[b * HID_ + gc] : hcbp[gc * 4 + b];
        xs[b * 32 + i] = hval * rs[b] * n1[l * HID_ + gc];
      }
      __syncthreads();
      float a0 = 0.f, a1 = 0.f, a2 = 0.f, a3 = 0.f;
      #pragma unroll
      for (int i = 0; i < 32; ++i) {
        float w = wv[i];
        a0 += w * xs[i]; a1 += w * xs[32 + i];
        a2 += w * xs[64 + i]; a3 += w * xs[96 + i];
      }
      stg_a(qp_ + ((size_t)(0 * 2048 + col)) * 32 + kc, a0);
      stg_a(qp_ + ((size_t)(1 * 2048 + col)) * 32 + kc, a1);
      stg_a(qp_ + ((size_t)(2 * 2048 + col)) * 32 + kc, a2);
      stg_a(qp_ + ((size_t)(3 * 2048 + col)) * 32 + kc, a3);
      __syncthreads();
      fadd(flg, FI(l, 0));
    }

    // ================= ATTN phase (all 512 blocks, 2 sub-chunks) =============
    {
      int w = t >> 6, lane = t & 63, r = lane >> 4, c = lane & 15;
      float* Kst = smem;          float* Vst = smem + 4352;
      float* qL  = smem + 8704;   float* knL = smem + 8832;
      float* vnL = smem + 8896;   float* rawL = smem + 8960;
      float* sA  = smem + 9216;   float* sB  = smem + 9280;
      float* red = smem + 9344;   float* oacc = smem + 9360;

      // hoist sub0 KV before the wait
      float4 kr[4], vr[4];
      {
        int cid = bid, bh = cid >> 5, ns = cid & 31, s0 = ns * 64;
        if (s0 <= pos) {
          const float4* Ks = (const float4*)(kcache + (((size_t)l * B_ + (bh >> 3)) * HKV_ + (bh & 7)) * S_ * 64 + (size_t)s0 * 64);
          const float4* Vs = (const float4*)(vcache + (((size_t)l * B_ + (bh >> 3)) * HKV_ + (bh & 7)) * S_ * 64 + (size_t)s0 * 64);
          #pragma unroll
          for (int i = 0; i < 4; ++i) { int f4 = t + i * 256; kr[i] = Ks[f4]; vr[i] = Vs[f4]; }
        }
      }
      fwait(flg, FI(l, 0), 256);

      #pragma unroll 1
      for (int sub = 0; sub < 2; ++sub) {
        int cid = bid + sub * 512;
        int bh = cid >> 5, ns = cid & 31;
        int b = bh >> 3, kv = bh & 7;
        int s0 = ns * 64;
        if (sub == 1 && s0 <= pos) {
          const float4* Ks = (const float4*)(kcache + (((size_t)l * B_ + b) * HKV_ + kv) * S_ * 64 + (size_t)s0 * 64);
          const float4* Vs = (const float4*)(vcache + (((size_t)l * B_ + b) * HKV_ + kv) * S_ * 64 + (size_t)s0 * 64);
          #pragma unroll
          for (int i = 0; i < 4; ++i) { int f4 = t + i * 256; kr[i] = Ks[f4]; vr[i] = Vs[f4]; }
        }
        if (s0 > pos) {
          if (t == 0) {
            int base = ((b * HKV_ + kv) * 2) * 32 + ns;
            stg_a(am_ + base, -1e30f);        stg_a(am_ + base + 32, -1e30f);
            stg_a(al_ + base, 0.f);           stg_a(al_ + base + 32, 0.f);
          }
        } else {
          // stage LDS
          #pragma unroll
          for (int i = 0; i < 4; ++i) {
            int f4 = t + i * 256;
            int row = f4 >> 4, c4 = f4 & 15;
            *(float4*)&Kst[row * 68 + 4 * c4] = kr[i];
            *(float4*)&Vst[row * 68 + 4 * c4] = vr[i];
          }
          // combine QP (contiguous 32) + rope
          int cg;
          if (t < 128)      cg = (kv * 2 + (t >> 6)) * 64 + (t & 63);
          else if (t < 192) cg = 1024 + kv * 64 + (t & 63);
          else              cg = 1536 + kv * 64 + (t & 63);
          const float* qpp = qp_ + ((size_t)(b * 2048 + cg)) * 32;
          float s = 0.f;
          #pragma unroll
          for (int q = 0; q < 32; ++q) s += qpp[q];
          rawL[t] = s;
          __syncthreads();
          {
            int dd = t & 63;
            if (t < 192) {
              int idx = dd & 31;
              float inv = expf(-(float)idx * (1.0f / 32.0f) * 9.210340371976184f);
              float ang = (float)pos * inv;
              float sn, cs; __sincosf(ang, &sn, &cs);
              float partner = rawL[t ^ 32];
              float rot = (dd < 32) ? -partner : partner;
              float v = rawL[t] * cs + rot * sn;
              if (t < 128) qL[(t >> 6) * 64 + dd] = v;
              else {
                knL[dd] = v;
                if (ns == 0) out[OUT_K + (((size_t)l * B_ + b) * HKV_ + kv) * 64 + dd] = v;
              }
            } else {
              vnL[dd] = rawL[t];
              if (ns == 0) out[OUT_V + (((size_t)l * B_ + b) * HKV_ + kv) * 64 + dd] = rawL[t];
            }
          }
          __syncthreads();
          if (pos >= s0 && pos < s0 + 64) {
            int row = pos - s0;
            if (t < 64)       Kst[row * 68 + t] = knL[t];
            else if (t < 128) Vst[row * 68 + (t - 64)] = vnL[t - 64];
          }
          __syncthreads();
          float4 q0 = *(float4*)&qL[4 * c];
          float4 q1 = *(float4*)&qL[64 + 4 * c];
          #pragma unroll
          for (int it = 0; it < 4; ++it) {
            int row = it * 16 + w * 4 + r;
            int sp = s0 + row;
            float4 k4 = *(float4*)&Kst[row * 68 + 4 * c];
            float d0 = k4.x * q0.x + k4.y * q0.y + k4.z * q0.z + k4.w * q0.w;
            float d1 = k4.x * q1.x + k4.y * q1.y + k4.z * q1.z + k4.w * q1.w;
            #pragma unroll
            for (int m = 1; m <= 8; m <<= 1) { d0 += __shfl_xor(d0, m); d1 += __shfl_xor(d1, m); }
            if (c == 0) {
              bool valid = (sp <= pos);
              sA[row] = valid ? d0 * SCALE_ : -1e30f;
              sB[row] = valid ? d1 * SCALE_ : -1e30f;
            }
          }
          __syncthreads();
          float v0 = (t < 64) ? sA[t] : -1e30f;
          float v1 = (t < 64) ? sB[t] : -1e30f;
          float m0 = wave_max(v0), m1 = wave_max(v1);
          if (lane == 0) { red[w] = m0; red[4 + w] = m1; }
          __syncthreads();
          m0 = fmaxf(fmaxf(red[0], red[1]), fmaxf(red[2], red[3]));
          m1 = fmaxf(fmaxf(red[4], red[5]), fmaxf(red[6], red[7]));
          float e0 = (t < 64) ? expf(v0 - m0) : 0.f;
          float e1 = (t < 64) ? expf(v1 - m1) : 0.f;
          __syncthreads();
          if (t < 64) { sA[t] = e0; sB[t] = e1; }
          float se0 = wave_sum(e0), se1 = wave_sum(e1);
          if (lane == 0) { red[w] = se0; red[4 + w] = se1; }
          __syncthreads();
          if (t == 0) {
            int base = ((b * HKV_ + kv) * 2) * 32 + ns;
            stg_a(am_ + base, m0);          stg_a(am_ + base + 32, m1);
            stg_a(al_ + base, red[0] + red[1] + red[2] + red[3]);
            stg_a(al_ + base + 32, red[4] + red[5] + red[6] + red[7]);
          }
          float4 a0 = make_float4(0.f, 0.f, 0.f, 0.f);
          float4 a1 = make_float4(0.f, 0.f, 0.f, 0.f);
          #pragma unroll
          for (int it = 0; it < 4; ++it) {
            int row = it * 16 + w * 4 + r;
            float4 v4 = *(float4*)&Vst[row * 68 + 4 * c];
            float p0 = sA[row], p1 = sB[row];
            a0.x += p0 * v4.x; a0.y += p0 * v4.y; a0.z += p0 * v4.z; a0.w += p0 * v4.w;
            a1.x += p1 * v4.x; a1.y += p1 * v4.y; a1.z += p1 * v4.z; a1.w += p1 * v4.w;
          }
          #pragma unroll
          for (int m = 16; m <= 32; m <<= 1) {
            a0.x += __shfl_xor(a0.x, m); a0.y += __shfl_xor(a0.y, m);
            a0.z += __shfl_xor(a0.z, m); a0.w += __shfl_xor(a0.w, m);
            a1.x += __shfl_xor(a1.x, m); a1.y += __shfl_xor(a1.y, m);
            a1.z += __shfl_xor(a1.z, m); a1.w += __shfl_xor(a1.w, m);
          }
          if (r == 0) {
            *(float4*)&oacc[w * 64 + 4 * c] = a0;
            *(float4*)&oacc[256 + w * 64 + 4 * c] = a1;
          }
          __syncthreads();
          if (t < 64) {
            float r0 = oacc[t] + oacc[64 + t] + oacc[128 + t] + oacc[192 + t];
            float r1 = oacc[256 + t] + oacc[320 + t] + oacc[384 + t] + oacc[448 + t];
            int h0 = kv * 2;
            stg_a(ao_ + (((size_t)(b * 16 + h0))     * 64 + t) * 32 + ns, r0);
            stg_a(ao_ + (((size_t)(b * 16 + h0 + 1)) * 64 + t) * 32 + ns, r1);
          }
        }
        __syncthreads();   // LDS handoff between subs / before flag
      }
      fadd(flg, FI(l, 1));
    }

    // ================= OPROJ phase (bid < 256) =================
    if (bid < 256) {
      int cb = bid & 3, kc = bid >> 2;     // 64 kc of 16 rows
      int col = cb * 256 + t;
      const float* wp = Wo + ((size_t)l * HID_ + kc * 16) * HID_ + col;
      float wv[16];
      #pragma unroll
      for (int i = 0; i < 16; ++i) wv[i] = wp[(size_t)i * HID_];
      fwait(flg, FI(l, 1), 512);
      float* oT = smem;    // 64 floats [jj*4+bb]
      if (t < 64) {
        int jj = t >> 2, bb = t & 3;
        int dim = kc * 16 + jj, h = dim >> 6, d = dim & 63;
        const float* amp = am_ + ((bb * 8 + (h >> 1)) * 2 + (h & 1)) * 32;
        const float* alp = al_ + ((bb * 8 + (h >> 1)) * 2 + (h & 1)) * 32;
        const float* aop = ao_ + (((size_t)(bb * 16 + h)) * 64 + d) * 32;
        float mx = -1e30f;
        #pragma unroll
        for (int n = 0; n < 32; ++n) mx = fmaxf(mx, amp[n]);
        float ls = 0.f, os = 0.f;
        #pragma unroll
        for (int n = 0; n < 32; ++n) {
          float wg = expf(amp[n] - mx);
          ls += wg * alp[n];
          os += wg * aop[n];
        }
        oT[jj * 4 + bb] = os / ls;
      }
      __syncthreads();
      float a0 = 0.f, a1 = 0.f, a2 = 0.f, a3 = 0.f;
      #pragma unroll
      for (int i = 0; i < 16; ++i) {
        float w = wv[i];
        a0 += w * oT[i * 4 + 0]; a1 += w * oT[i * 4 + 1];
        a2 += w * oT[i * 4 + 2]; a3 += w * oT[i * 4 + 3];
      }
      atomicAdd(hca_ + col * 4 + 0, MUP_ * a0);
      atomicAdd(hca_ + col * 4 + 1, MUP_ * a1);
      atomicAdd(hca_ + col * 4 + 2, MUP_ * a2);
      atomicAdd(hca_ + col * 4 + 3, MUP_ * a3);
      __syncthreads();
      fadd(flg, FI(l, 2));
    }

    // ================= GATEUP phase (bid < 352) =================
    if (bid < 352) {
      int cb = bid % 11, kc = bid / 11;
      int col = cb * 256 + t;
      const float* wgp = Wg + ((size_t)l * HID_ + kc * 32) * FF_ + col;
      const float* wup = Wu + ((size_t)l * HID_ + kc * 32) * FF_ + col;
      float gv[32], uv[32];
      #pragma unroll
      for (int i = 0; i < 32; ++i) { gv[i] = wgp[(size_t)i * FF_]; uv[i] = wup[(size_t)i * FF_]; }
      fwait(flg, FI(l, 2), 256);
      float4 h4[4];
      #pragma unroll
      for (int j = 0; j < 4; ++j) h4[j] = *(const float4*)&hca_[(t + j * 256) * 4];
      float part[4] = {0.f, 0.f, 0.f, 0.f};
      #pragma unroll
      for (int j = 0; j < 4; ++j) {
        part[0] += h4[j].x * h4[j].x; part[1] += h4[j].y * h4[j].y;
        part[2] += h4[j].z * h4[j].z; part[3] += h4[j].w * h4[j].w;
      }
      float* red = smem;
      float* xs  = smem + 16;
      int w_ = t >> 6;
      #pragma unroll
      for (int b = 0; b < 4; ++b) {
        float s = wave_sum(part[b]);
        if ((t & 63) == 0) red[w_ * 4 + b] = s;
      }
      __syncthreads();
      float rs[4];
      #pragma unroll
      for (int b = 0; b < 4; ++b)
        rs[b] = rsqrtf((red[b] + red[4 + b] + red[8 + b] + red[12 + b]) * (1.0f / HID_) + EPS_);
      if (bid < 4) {  // seed HCB[l]
        #pragma unroll
        for (int j = 0; j < 4; ++j) {
          int c2 = t + j * 256;
          float v = (bid == 0) ? h4[j].x : (bid == 1) ? h4[j].y : (bid == 2) ? h4[j].z : h4[j].w;
          stg_a(hcb_ + c2 * 4 + bid, v);
        }
      }
      if (t < 128) {
        int b = t >> 5, i = t & 31;
        int gc = kc * 32 + i;
        xs[b * 32 + i] = hca_[gc * 4 + b] * rs[b] * n2[l * HID_ + gc];
      }
      __syncthreads();
      float g0 = 0.f, g1 = 0.f, g2 = 0.f, g3 = 0.f;
      float u0 = 0.f, u1 = 0.f, u2 = 0.f, u3 = 0.f;
      #pragma unroll
      for (int i = 0; i < 32; ++i) {
        float g = gv[i], u = uv[i];
        float x0 = xs[i], x1 = xs[32 + i], x2 = xs[64 + i], x3 = xs[96 + i];
        g0 += g * x0; g1 += g * x1; g2 += g * x2; g3 += g * x3;
        u0 += u * x0; u1 += u * x1; u2 += u * x2; u3 += u * x3;
      }
      stg_a(gp_ + ((size_t)(0 * FF_ + col)) * 32 + kc, g0);
      stg_a(gp_ + ((size_t)(1 * FF_ + col)) * 32 + kc, g1);
      stg_a(gp_ + ((size_t)(2 * FF_ + col)) * 32 + kc, g2);
      stg_a(gp_ + ((size_t)(3 * FF_ + col)) * 32 + kc, g3);
      stg_a(up_ + ((size_t)(0 * FF_ + col)) * 32 + kc, u0);
      stg_a(up_ + ((size_t)(1 * FF_ + col)) * 32 + kc, u1);
      stg_a(up_ + ((size_t)(2 * FF_ + col)) * 32 + kc, u2);
      stg_a(up_ + ((size_t)(3 * FF_ + col)) * 32 + kc, u3);
      __syncthreads();
      fadd(flg, FI(l, 3));
    }

    // ================= DOWN phase (bid < 352) =================
    if (bid < 352) {
      int cb = bid & 3, kc = bid >> 2;   // 88 kc of 32 rows
      int col = cb * 256 + t;
      const float* wp = Wd + ((size_t)l * FF_ + kc * 32) * HID_ + col;
      float wv[32];
      #pragma unroll
      for (int i = 0; i < 32; ++i) wv[i] = wp[(size_t)i * HID_];
      fwait(flg, FI(l, 3), 352);
      float* mT = smem;   // 128 floats [jj*4+bb]
      if (t < 128) {
        int jj = t >> 2, bb = t & 3;
        int f = kc * 32 + jj;
        const float* gpp = gp_ + ((size_t)(bb * FF_ + f)) * 32;
        const float* upp = up_ + ((size_t)(bb * FF_ + f)) * 32;
        float g = 0.f, u = 0.f;
        #pragma unroll
        for (int q = 0; q < 32; ++q) { g += gpp[q]; u += upp[q]; }
        float sig = 1.f / (1.f + expf(-g));
        mT[jj * 4 + bb] = g * sig * u;
      }
      __syncthreads();
      float a0 = 0.f, a1 = 0.f, a2 = 0.f, a3 = 0.f;
      #pragma unroll
      for (int i = 0; i < 32; ++i) {
        float w = wv[i];
        a0 += w * mT[i * 4 + 0]; a1 += w * mT[i * 4 + 1];
        a2 += w * mT[i * 4 + 2]; a3 += w * mT[i * 4 + 3];
      }
      atomicAdd(hcb_ + col * 4 + 0, MUP_ * a0);
      atomicAdd(hcb_ + col * 4 + 1, MUP_ * a1);
      atomicAdd(hcb_ + col * 4 + 2, MUP_ * a2);
      atomicAdd(hcb_ + col * 4 + 3, MUP_ * a3);
      __syncthreads();
      fadd(flg, FI(l, 4));
    }
  }

  // ================= FINAL (blocks 0-3) =================
  if (bid < 4) {
    fwait(flg, FI(L_ - 1, 4), 352);
    const float* hcb7 = ws + (size_t)(L_ - 1) * PL_SZ + PL_HCB;
    int b = bid;
    float* red = smem;
    float hv[4];
    float part = 0.f;
    #pragma unroll
    for (int j = 0; j < 4; ++j) {
      float v = hcb7[(t + j * 256) * 4 + b];
      hv[j] = v; part += v * v;
    }
    part = wave_sum(part);
    if ((t & 63) == 0) red[t >> 6] = part;
    __syncthreads();
    float rs = rsqrtf((red[0] + red[1] + red[2] + red[3]) * (1.0f / HID_) + EPS_);
    #pragma unroll
    for (int j = 0; j < 4; ++j) {
      int c2 = t + j * 256;
      out[OUT_H + b * HID_ + c2] = hv[j] * rs * fw[c2];
    }
  }
}

// ======================= FALLBACK: proven R10 multi-kernel ===================
enum {
  WS_HC  = 0,
  WS_QP  = 4096,
  WS_AM  = WS_QP + 262144,
  WS_AL  = WS_AM + 2048,
  WS_AO  = WS_AL + 2048,
  WS_GP  = WS_AO + 131072,
  WS_UP  = WS_GP + 360448,
  WS_END = WS_UP + 360448
};

__device__ __forceinline__ void rms_of(const float* hsrc, float* red, float* rs) {
  int t = threadIdx.x;
  float part[4] = {0.f, 0.f, 0.f, 0.f};
  #pragma unroll
  for (int j = 0; j < 4; ++j) {
    int c2 = t + j * 256;
    #pragma unroll
    for (int b = 0; b < 4; ++b) { float v = hsrc[b * HID_ + c2]; part[b] += v * v; }
  }
  int w = t >> 6;
  #pragma unroll
  for (int b = 0; b < 4; ++b) {
    float s = wave_sum(part[b]);
    if ((t & 63) == 0) red[w * 4 + b] = s;
  }
  __syncthreads();
  #pragma unroll
  for (int b = 0; b < 4; ++b)
    rs[b] = rsqrtf((red[b] + red[4 + b] + red[8 + b] + red[12 + b]) * (1.0f / HID_) + EPS_);
}

__global__ void __launch_bounds__(256)
k1_qkv(const float* __restrict__ Wq, const float* __restrict__ Wk,
       const float* __restrict__ Wv, const float* __restrict__ n1,
       const float* __restrict__ x, float* __restrict__ ws, int l) {
  int cb = blockIdx.x & 7, kc = blockIdx.x >> 3;
  int t = threadIdx.x;
  int col = cb * 256 + t;
  const float* W; int wcol, stride;
  if (col < 1024)      { W = Wq + (size_t)l * HID_ * 1024; wcol = col;        stride = 1024; }
  else if (col < 1536) { W = Wk + (size_t)l * HID_ * 512;  wcol = col - 1024; stride = 512;  }
  else                 { W = Wv + (size_t)l * HID_ * 512;  wcol = col - 1536; stride = 512;  }
  const float* wp = W + (size_t)(kc * 32) * stride + wcol;
  float wv[32];
  #pragma unroll
  for (int i = 0; i < 32; ++i) wv[i] = wp[(size_t)i * stride];
  const float* hsrc = (l == 0) ? x : (ws + WS_HC);
  __shared__ float red[16];
  __shared__ __align__(16) float xs[4][32];
  float rs[4];
  rms_of(hsrc, red, rs);
  if (l == 0 && blockIdx.x < 4) {
    for (int j = 0; j < 4; ++j) {
      int c2 = t + j * 256;
      ws[WS_HC + blockIdx.x * HID_ + c2] = x[blockIdx.x * HID_ + c2];
    }
  }
  if (t < 128) {
    int b = t >> 5, i = t & 31;
    int gc = kc * 32 + i;
    xs[b][i] = hsrc[b * HID_ + gc] * rs[b] * n1[l * HID_ + gc];
  }
  __syncthreads();
  float a0 = 0.f, a1 = 0.f, a2 = 0.f, a3 = 0.f;
  #pragma unroll
  for (int i = 0; i < 32; ++i) {
    float w_ = wv[i];
    a0 += w_ * xs[0][i]; a1 += w_ * xs[1][i];
    a2 += w_ * xs[2][i]; a3 += w_ * xs[3][i];
  }
  ws[WS_QP + ((size_t)kc * 4 + 0) * 2048 + col] = a0;
  ws[WS_QP + ((size_t)kc * 4 + 1) * 2048 + col] = a1;
  ws[WS_QP + ((size_t)kc * 4 + 2) * 2048 + col] = a2;
  ws[WS_QP + ((size_t)kc * 4 + 3) * 2048 + col] = a3;
}

__global__ void __launch_bounds__(256)
k2_attn(const float* __restrict__ kcache, const float* __restrict__ vcache,
        const int* __restrict__ posp, float* __restrict__ ws,
        float* __restrict__ out, int l) {
  int bh = blockIdx.x >> 5, ns = blockIdx.x & 31;
  int b = bh >> 3, kv = bh & 7;
  int t = threadIdx.x;
  int w = t >> 6, lane = t & 63, r = lane >> 4, c = lane & 15;
  int pos = read_pos_dev(posp);
  int s0 = ns * 64;
  if (s0 > pos) {
    if (t == 0) {
      int base = ((b * HKV_ + kv) * 2) * NCH_ + ns;
      ws[WS_AM + base] = -1e30f;       ws[WS_AM + base + NCH_] = -1e30f;
      ws[WS_AL + base] = 0.f;          ws[WS_AL + base + NCH_] = 0.f;
    }
    return;
  }
  __shared__ __align__(16) float Kst[64 * 68];
  __shared__ __align__(16) float Vst[64 * 68];
  __shared__ __align__(16) float qL[2][64];
  __shared__ __align__(16) float knL[64], vnL[64];
  __shared__ float rawL[256], sc0[64], sc1[64], red[8];
  __shared__ __align__(16) float oacc[2][4][64];
  const float* Kb = kcache + (((size_t)l * B_ + b) * HKV_ + kv) * S_ * 64;
  const float* Vb = vcache + (((size_t)l * B_ + b) * HKV_ + kv) * S_ * 64;
  {
    const float4* Ksrc = (const float4*)(Kb + (size_t)s0 * 64);
    const float4* Vsrc = (const float4*)(Vb + (size_t)s0 * 64);
    #pragma unroll
    for (int i = 0; i < 4; ++i) {
      int f4 = t + i * 256;
      int row = f4 >> 4, c4 = f4 & 15;
      float4 kk = Ksrc[f4];
      float4 vv = Vsrc[f4];
      *(float4*)&Kst[row * 68 + 4 * c4] = kk;
      *(float4*)&Vst[row * 68 + 4 * c4] = vv;
    }
  }
  int cg;
  if (t < 128)      cg = (kv * 2 + (t >> 6)) * 64 + (t & 63);
  else if (t < 192) cg = 1024 + kv * 64 + (t & 63);
  else              cg = 1536 + kv * 64 + (t & 63);
  float s = 0.f;
  #pragma unroll
  for (int q = 0; q < 32; ++q) s += ws[WS_QP + ((size_t)q * 4 + b) * 2048 + cg];
  rawL[t] = s;
  __syncthreads();
  {
    int dd = t & 63;
    if (t < 192) {
      int idx = dd & 31;
      float inv = expf(-(float)idx * (1.0f / 32.0f) * 9.210340371976184f);
      float ang = (float)pos * inv;
      float sn, cs; __sincosf(ang, &sn, &cs);
      float partner = rawL[t ^ 32];
      float rot = (dd < 32) ? -partner : partner;
      float v = rawL[t] * cs + rot * sn;
      if (t < 128) qL[t >> 6][dd] = v;
      else {
        knL[dd] = v;
        if (ns == 0) out[OUT_K + (((size_t)l * B_ + b) * HKV_ + kv) * 64 + dd] = v;
      }
    } else {
      vnL[dd] = rawL[t];
      if (ns == 0) out[OUT_V + (((size_t)l * B_ + b) * HKV_ + kv) * 64 + dd] = rawL[t];
    }
  }
  __syncthreads();
  if (pos >= s0 && pos < s0 + 64) {
    int row = pos - s0;
    if (t < 64)       Kst[row * 68 + t] = knL[t];
    else if (t < 128) Vst[row * 68 + (t - 64)] = vnL[t - 64];
  }
  __syncthreads();
  float4 q0 = *(float4*)&qL[0][4 * c];
  float4 q1 = *(float4*)&qL[1][4 * c];
  #pragma unroll
  for (int it = 0; it < 4; ++it) {
    int row = it * 16 + w * 4 + r;
    int sp = s0 + row;
    float4 k4 = *(float4*)&Kst[row * 68 + 4 * c];
    float d0 = k4.x * q0.x + k4.y * q0.y + k4.z * q0.z + k4.w * q0.w;
    float d1 = k4.x * q1.x + k4.y * q1.y + k4.z * q1.z + k4.w * q1.w;
    #pragma unroll
    for (int m = 1; m <= 8; m <<= 1) { d0 += __shfl_xor(d0, m); d1 += __shfl_xor(d1, m); }
    if (c == 0) {
      bool valid = (sp <= pos);
      sc0[row] = valid ? d0 * SCALE_ : -1e30f;
      sc1[row] = valid ? d1 * SCALE_ : -1e30f;
    }
  }
  __syncthreads();
  float v0 = (t < 64) ? sc0[t] : -1e30f;
  float v1 = (t < 64) ? sc1[t] : -1e30f;
  float m0 = wave_max(v0), m1 = wave_max(v1);
  if (lane == 0) { red[w] = m0; red[4 + w] = m1; }
  __syncthreads();
  m0 = fmaxf(fmaxf(red[0], red[1]), fmaxf(red[2], red[3]));
  m1 = fmaxf(fmaxf(red[4], red[5]), fmaxf(red[6], red[7]));
  float e0 = (t < 64) ? expf(v0 - m0) : 0.f;
  float e1 = (t < 64) ? expf(v1 - m1) : 0.f;
  __syncthreads();
  if (t < 64) { sc0[t] = e0; sc1[t] = e1; }
  float se0 = wave_sum(e0), se1 = wave_sum(e1);
  if (lane == 0) { red[w] = se0; red[4 + w] = se1; }
  __syncthreads();
  if (t == 0) {
    int base = ((b * HKV_ + kv) * 2) * NCH_ + ns;
    ws[WS_AM + base] = m0;          ws[WS_AM + base + NCH_] = m1;
    ws[WS_AL + base] = red[0] + red[1] + red[2] + red[3];
    ws[WS_AL + base + NCH_] = red[4] + red[5] + red[6] + red[7];
  }
  float4 a0 = make_float4(0.f, 0.f, 0.f, 0.f);
  float4 a1 = make_float4(0.f, 0.f, 0.f, 0.f);
  #pragma unroll
  for (int it = 0; it < 4; ++it) {
    int row = it * 16 + w * 4 + r;
    float4 v4 = *(float4*)&Vst[row * 68 + 4 * c];
    float p0 = sc0[row], p1 = sc1[row];
    a0.x += p0 * v4.x; a0.y += p0 * v4.y; a0.z += p0 * v4.z; a0.w += p0 * v4.w;
    a1.x += p1 * v4.x; a1.y += p1 * v4.y; a1.z += p1 * v4.z; a1.w += p1 * v4.w;
  }
  #pragma unroll
  for (int m = 16; m <= 32; m <<= 1) {
    a0.x += __shfl_xor(a0.x, m); a0.y += __shfl_xor(a0.y, m);
    a0.z += __shfl_xor(a0.z, m); a0.w += __shfl_xor(a0.w, m);
    a1.x += __shfl_xor(a1.x, m); a1.y += __shfl_xor(a1.y, m);
    a1.z += __shfl_xor(a1.z, m); a1.w += __shfl_xor(a1.w, m);
  }
  if (r == 0) {
    *(float4*)&oacc[0][w][4 * c] = a0;
    *(float4*)&oacc[1][w][4 * c] = a1;
  }
  __syncthreads();
  if (t < 64) {
    float r0 = oacc[0][0][t] + oacc[0][1][t] + oacc[0][2][t] + oacc[0][3][t];
    float r1 = oacc[1][0][t] + oacc[1][1][t] + oacc[1][2][t] + oacc[1][3][t];
    int h0 = kv * 2;
    ws[WS_AO + ((size_t)(b * H_ + h0)     * NCH_ + ns) * 64 + t] = r0;
    ws[WS_AO + ((size_t)(b * H_ + h0 + 1) * NCH_ + ns) * 64 + t] = r1;
  }
}

__global__ void __launch_bounds__(256)
k3_oproj(const float* __restrict__ Wo, float* __restrict__ ws, int l) {
  int cb = blockIdx.x & 3, kc = blockIdx.x >> 2;
  int t = threadIdx.x;
  int col = cb * 256 + t;
  const float* wp = Wo + ((size_t)l * HID_ + kc * 16) * HID_ + col;
  float wv[16];
  #pragma unroll
  for (int i = 0; i < 16; ++i) wv[i] = wp[(size_t)i * HID_];
  __shared__ __align__(16) float oT[16][4];
  if (t < 64) {
    int jj = t >> 2, bb = t & 3;
    int dim = kc * 16 + jj, h = dim >> 6, d = dim & 63;
    int mb = ((bb * HKV_ + (h >> 1)) * 2 + (h & 1)) * NCH_;
    float mx = -1e30f;
    #pragma unroll
    for (int n = 0; n < NCH_; ++n) mx = fmaxf(mx, ws[WS_AM + mb + n]);
    float ls = 0.f, os = 0.f;
    #pragma unroll
    for (int n = 0; n < NCH_; ++n) {
      float wg = expf(ws[WS_AM + mb + n] - mx);
      ls += wg * ws[WS_AL + mb + n];
      os += wg * ws[WS_AO + ((size_t)(bb * H_ + h) * NCH_ + n) * 64 + d];
    }
    oT[jj][bb] = os / ls;
  }
  __syncthreads();
  float a0 = 0.f, a1 = 0.f, a2 = 0.f, a3 = 0.f;
  #pragma unroll
  for (int i = 0; i < 16; ++i) {
    float w_ = wv[i];
    float4 o4 = *(float4*)&oT[i][0];
    a0 += w_ * o4.x; a1 += w_ * o4.y; a2 += w_ * o4.z; a3 += w_ * o4.w;
  }
  atomicAdd(ws + WS_HC + 0 * HID_ + col, MUP_ * a0);
  atomicAdd(ws + WS_HC + 1 * HID_ + col, MUP_ * a1);
  atomicAdd(ws + WS_HC + 2 * HID_ + col, MUP_ * a2);
  atomicAdd(ws + WS_HC + 3 * HID_ + col, MUP_ * a3);
}

__global__ void __launch_bounds__(256)
k4_gateup(const float* __restrict__ Wg, const float* __restrict__ Wu,
          const float* __restrict__ n2, float* __restrict__ ws, int l) {
  int cb = blockIdx.x % 11, kc = blockIdx.x / 11;
  int t = threadIdx.x;
  int col = cb * 256 + t;
  const float* wgp = Wg + ((size_t)l * HID_ + kc * 32) * FF_ + col;
  const float* wup = Wu + ((size_t)l * HID_ + kc * 32) * FF_ + col;
  float gv[32], uv[32];
  #pragma unroll
  for (int i = 0; i < 32; ++i) { gv[i] = wgp[(size_t)i * FF_]; uv[i] = wup[(size_t)i * FF_]; }
  const float* hsrc = ws + WS_HC;
  __shared__ float red[16];
  __shared__ __align__(16) float xs[4][32];
  float rs[4];
  rms_of(hsrc, red, rs);
  if (t < 128) {
    int b = t >> 5, i = t & 31;
    int gc = kc * 32 + i;
    xs[b][i] = hsrc[b * HID_ + gc] * rs[b] * n2[l * HID_ + gc];
  }
  __syncthreads();
  float g0 = 0.f, g1 = 0.f, g2 = 0.f, g3 = 0.f;
  float u0 = 0.f, u1 = 0.f, u2 = 0.f, u3 = 0.f;
  #pragma unroll
  for (int i = 0; i < 32; ++i) {
    float g = gv[i], u = uv[i];
    float x0 = xs[0][i], x1 = xs[1][i], x2 = xs[2][i], x3 = xs[3][i];
    g0 += g * x0; g1 += g * x1; g2 += g * x2; g3 += g * x3;
    u0 += u * x0; u1 += u * x1; u2 += u * x2; u3 += u * x3;
  }
  ws[WS_GP + ((size_t)kc * 4 + 0) * FF_ + col] = g0;
  ws[WS_GP + ((size_t)kc * 4 + 1) * FF_ + col] = g1;
  ws[WS_GP + ((size_t)kc * 4 + 2) * FF_ + col] = g2;
  ws[WS_GP + ((size_t)kc * 4 + 3) * FF_ + col] = g3;
  ws[WS_UP + ((size_t)kc * 4 + 0) * FF_ + col] = u0;
  ws[WS_UP + ((size_t)kc * 4 + 1) * FF_ + col] = u1;
  ws[WS_UP + ((size_t)kc * 4 + 2) * FF_ + col] = u2;
  ws[WS_UP + ((size_t)kc * 4 + 3) * FF_ + col] = u3;
}

__global__ void __launch_bounds__(256)
k5_down(const float* __restrict__ Wd, float* __restrict__ ws, int l) {
  int cb = blockIdx.x & 3, kc = blockIdx.x >> 2;
  int t = threadIdx.x;
  int col = cb * 256 + t;
  const float* wp = Wd + ((size_t)l * FF_ + kc * 32) * HID_ + col;
  float wv[32];
  #pragma unroll
  for (int i = 0; i < 32; ++i) wv[i] = wp[(size_t)i * HID_];
  __shared__ __align__(16) float mT[32][4];
  if (t < 128) {
    int jj = t >> 2, bb = t & 3;
    int f = kc * 32 + jj;
    float g = 0.f, u = 0.f;
    #pragma unroll
    for (int k2 = 0; k2 < 32; ++k2) {
      g += ws[WS_GP + ((size_t)k2 * 4 + bb) * FF_ + f];
      u += ws[WS_UP + ((size_t)k2 * 4 + bb) * FF_ + f];
    }
    float sig = 1.f / (1.f + expf(-g));
    mT[jj][bb] = g * sig * u;
  }
  __syncthreads();
  float a0 = 0.f, a1 = 0.f, a2 = 0.f, a3 = 0.f;
  #pragma unroll
  for (int i = 0; i < 32; ++i) {
    float w_ = wv[i];
    float4 m4 = *(float4*)&mT[i][0];
    a0 += w_ * m4.x; a1 += w_ * m4.y; a2 += w_ * m4.z; a3 += w_ * m4.w;
  }
  atomicAdd(ws + WS_HC + 0 * HID_ + col, MUP_ * a0);
  atomicAdd(ws + WS_HC + 1 * HID_ + col, MUP_ * a1);
  atomicAdd(ws + WS_HC + 2 * HID_ + col, MUP_ * a2);
  atomicAdd(ws + WS_HC + 3 * HID_ + col, MUP_ * a3);
}

__global__ void __launch_bounds__(256)
k6_final(const float* __restrict__ fw, const int* __restrict__ posp,
         float* __restrict__ ws, float* __restrict__ out) {
  int b = blockIdx.x, t = threadIdx.x;
  __shared__ float red[4];
  float hv[4];
  float part = 0.f;
  for (int j = 0; j < 4; ++j) {
    float v = ws[WS_HC + b * HID_ + t + j * 256];
    hv[j] = v; part += v * v;
  }
  part = wave_sum(part);
  if ((t & 63) == 0) red[t >> 6] = part;
  __syncthreads();
  float rs = rsqrtf((red[0] + red[1] + red[2] + red[3]) * (1.0f / HID_) + EPS_);
  for (int j = 0; j < 4; ++j) {
    int c2 = t + j * 256;
    out[OUT_H + b * HID_ + c2] = hv[j] * rs * fw[c2];
  }
  if (b == 0 && t == 0) out[OUT_POS] = (float)(read_pos_dev(posp) + 1);
}

extern "C" void kernel_launch(void* const* d_in, const int* in_sizes, int n_in,
                              void* d_out, int out_size, void* d_ws, size_t ws_size,
                              hipStream_t stream) {
  const float* x   = (const float*)d_in[0];
  const float* kcp = (const float*)d_in[1];
  const float* vcp = (const float*)d_in[2];
  const float* Wq  = (const float*)d_in[3];
  const float* Wk  = (const float*)d_in[4];
  const float* Wv  = (const float*)d_in[5];
  const float* Wo  = (const float*)d_in[6];
  const float* Wg  = (const float*)d_in[7];
  const float* Wu  = (const float*)d_in[8];
  const float* Wd  = (const float*)d_in[9];
  const float* n1  = (const float*)d_in[10];
  const float* n2  = (const float*)d_in[11];
  const float* fw  = (const float*)d_in[12];
  const int*   pos = (const int*)d_in[13];
  float* ws  = (float*)d_ws;
  float* out = (float*)d_out;

  if (ws_size >= (size_t)NEED_FLOATS * sizeof(float)) {
    k_init<<<4, 256, 0, stream>>>(ws);
    void* args[] = { (void*)&kcp, (void*)&vcp, (void*)&Wq, (void*)&Wk, (void*)&Wv,
                     (void*)&Wo, (void*)&Wg, (void*)&Wu, (void*)&Wd, (void*)&n1,
                     (void*)&n2, (void*)&fw, (void*)&x, (void*)&pos,
                     (void*)&ws, (void*)&out };
    hipError_t e = hipLaunchCooperativeKernel((const void*)mega, dim3(512), dim3(256),
                                              args, 0, stream);
    if (e != hipSuccess) {
      mega<<<512, 256, 0, stream>>>(kcp, vcp, Wq, Wk, Wv, Wo, Wg, Wu, Wd,
                                    n1, n2, fw, x, pos, ws, out);
    }
  } else {
    for (int l = 0; l < L_; ++l) {
      k1_qkv   <<< 256, 256, 0, stream>>>(Wq, Wk, Wv, n1, x, ws, l);
      k2_attn  <<<1024, 256, 0, stream>>>(kcp, vcp, pos, ws, out, l);
      k3_oproj <<< 256, 256, 0, stream>>>(Wo, ws, l);
      k4_gateup<<< 352, 256, 0, stream>>>(Wg, Wu, n2, ws, l);
      k5_down  <<< 352, 256, 0, stream>>>(Wd, ws, l);
    }
    k6_final<<<4, 256, 0, stream>>>(fw, pos, ws, out);
  }
}

// Round 13
// 300.409 us; speedup vs baseline: 3.6803x; 3.6803x over previous
//
#include <hip/hip_runtime.h>

// MiniCPM-style decode step: L=8 B=4 H=16 HKV=8 D=64 S=2048 HID=1024 FF=2816
#define L_   8
#define B_   4
#define H_   16
#define HKV_ 8
#define D_   64
#define S_   2048
#define HID_ 1024
#define FF_  2816
#define EPS_ 1e-5f
#define MUP_ 0.49497474683058327f   // 1.4/sqrt(8)
#define SCALE_ 0.125f               // 1/sqrt(64)
#define NCH_ 32                     // attention chunks of 64 positions

// d_out is FLOAT32: [h 4096 | k_upd 16384 | v_upd 16384 | pos+1]
#define OUT_H   0
#define OUT_K   4096
#define OUT_V   (4096 + 16384)
#define OUT_POS (4096 + 16384 + 16384)

// ---------------- workspace layout (floats); partials [kc][b][col] ----------------
enum {
  WS_HC  = 0,                        // 4096   live hidden state (atomics target)
  WS_QP  = 4096,                     // 32*4*2048 = 262144
  WS_AM  = WS_QP + 262144,           // 2048   [b][kv][2][32]
  WS_AL  = WS_AM + 2048,             // 2048
  WS_AO  = WS_AL + 2048,             // 4*16*32*64 = 131072
  WS_GP  = WS_AO + 131072,           // 32*4*2816 = 360448
  WS_UP  = WS_GP + 360448,           // 360448
  WS_END = WS_UP + 360448            // ~4.5 MB
};

__device__ __forceinline__ int read_pos_dev(const int* p) {
  int v = p[0];
  if (v >= 0 && v < S_) return v;
  float f = __int_as_float(v);
  if (f >= 0.0f && f <= (float)(S_ - 1)) return (int)(f + 0.5f);
  return 1500;
}

__device__ __forceinline__ float wave_sum(float v) {
  for (int m = 1; m < 64; m <<= 1) v += __shfl_xor(v, m);
  return v;
}
__device__ __forceinline__ float wave_max(float v) {
  for (int m = 1; m < 64; m <<= 1) v = fmaxf(v, __shfl_xor(v, m));
  return v;
}

// shared RMS prologue: read 4x1024 h, per-batch rsqrt(mean sq)
__device__ __forceinline__ void rms_of(const float* hsrc, float* red, float* rs) {
  int t = threadIdx.x;
  float part[4] = {0.f, 0.f, 0.f, 0.f};
  #pragma unroll
  for (int j = 0; j < 4; ++j) {
    int c2 = t + j * 256;
    #pragma unroll
    for (int b = 0; b < 4; ++b) {
      float v = hsrc[b * HID_ + c2];
      part[b] += v * v;
    }
  }
  int w = t >> 6;
  #pragma unroll
  for (int b = 0; b < 4; ++b) {
    float s = wave_sum(part[b]);
    if ((t & 63) == 0) red[w * 4 + b] = s;
  }
  __syncthreads();
  #pragma unroll
  for (int b = 0; b < 4; ++b)
    rs[b] = rsqrtf((red[b] + red[4 + b] + red[8 + b] + red[12 + b]) * (1.0f / HID_) + EPS_);
}

// ================= K1: QKV GEMV (RMS prologue, no combine) =================
// grid 256 = 8 cb x 32 kc (32 rows each)
__global__ void __launch_bounds__(256)
k1_qkv(const float* __restrict__ Wq, const float* __restrict__ Wk,
       const float* __restrict__ Wv, const float* __restrict__ n1,
       const float* __restrict__ x, float* __restrict__ ws, int l) {
  int cb = blockIdx.x & 7, kc = blockIdx.x >> 3;
  int t = threadIdx.x;
  int col = cb * 256 + t;
  const float* W; int wcol, stride;
  if (col < 1024)      { W = Wq + (size_t)l * HID_ * 1024; wcol = col;        stride = 1024; }
  else if (col < 1536) { W = Wk + (size_t)l * HID_ * 512;  wcol = col - 1024; stride = 512;  }
  else                 { W = Wv + (size_t)l * HID_ * 512;  wcol = col - 1536; stride = 512;  }
  const float* wp = W + (size_t)(kc * 32) * stride + wcol;
  float wv[32];
  #pragma unroll
  for (int i = 0; i < 32; ++i) wv[i] = wp[(size_t)i * stride];   // in flight

  const float* hsrc = (l == 0) ? x : (ws + WS_HC);
  __shared__ float red[16];
  __shared__ __align__(16) float xs[4][32];
  float rs[4];
  rms_of(hsrc, red, rs);
  if (l == 0 && blockIdx.x < 4) {        // seed HC = x (blocks 0-3, one batch each)
    for (int j = 0; j < 4; ++j) {
      int c2 = t + j * 256;
      ws[WS_HC + blockIdx.x * HID_ + c2] = x[blockIdx.x * HID_ + c2];
    }
  }
  if (t < 128) {
    int b = t >> 5, i = t & 31;
    int gc = kc * 32 + i;
    xs[b][i] = hsrc[b * HID_ + gc] * rs[b] * n1[l * HID_ + gc];
  }
  __syncthreads();
  float a0 = 0.f, a1 = 0.f, a2 = 0.f, a3 = 0.f;
  #pragma unroll
  for (int i = 0; i < 32; ++i) {
    float w_ = wv[i];
    a0 += w_ * xs[0][i]; a1 += w_ * xs[1][i];
    a2 += w_ * xs[2][i]; a3 += w_ * xs[3][i];
  }
  ws[WS_QP + ((size_t)kc * 4 + 0) * 2048 + col] = a0;
  ws[WS_QP + ((size_t)kc * 4 + 1) * 2048 + col] = a1;
  ws[WS_QP + ((size_t)kc * 4 + 2) * 2048 + col] = a2;
  ws[WS_QP + ((size_t)kc * 4 + 3) * 2048 + col] = a3;
}

// ================= K2: qkv-combine + rope + kv-out + flash chunk (direct loads) ==
// grid 1024 = (b,kv) x 32 chunks of 64 positions; fully-masked chunks skip.
// No K/V LDS staging: per-lane float4 global reads have identical coalescing,
// LDS drops to ~4.6KB -> 8 blocks/CU for latency hiding.
__global__ void __launch_bounds__(256)
k2_attn(const float* __restrict__ kcache, const float* __restrict__ vcache,
        const int* __restrict__ posp, float* __restrict__ ws,
        float* __restrict__ out, int l) {
  int bh = blockIdx.x >> 5, ns = blockIdx.x & 31;
  int b = bh >> 3, kv = bh & 7;
  int t = threadIdx.x;
  int w = t >> 6, lane = t & 63, r = lane >> 4, c = lane & 15;
  int pos = read_pos_dev(posp);
  int s0 = ns * 64;
  if (s0 > pos) {                      // fully-masked chunk: sentinels, no traffic
    if (t == 0) {
      int base = ((b * HKV_ + kv) * 2) * NCH_ + ns;
      ws[WS_AM + base] = -1e30f;       ws[WS_AM + base + NCH_] = -1e30f;
      ws[WS_AL + base] = 0.f;          ws[WS_AL + base + NCH_] = 0.f;
    }
    return;
  }
  __shared__ __align__(16) float qL[2][64];
  __shared__ __align__(16) float knL[64], vnL[64];
  __shared__ float rawL[256], sc0[64], sc1[64], red[8];
  __shared__ __align__(16) float oacc[2][4][64];

  const float* Kb = kcache + (((size_t)l * B_ + b) * HKV_ + kv) * S_ * 64;
  const float* Vb = vcache + (((size_t)l * B_ + b) * HKV_ + kv) * S_ * 64;

  // combine qkv partials -> rawL; rope
  int cg;
  if (t < 128)      cg = (kv * 2 + (t >> 6)) * 64 + (t & 63);
  else if (t < 192) cg = 1024 + kv * 64 + (t & 63);
  else              cg = 1536 + kv * 64 + (t & 63);
  float s = 0.f;
  #pragma unroll
  for (int q = 0; q < 32; ++q) s += ws[WS_QP + ((size_t)q * 4 + b) * 2048 + cg];
  rawL[t] = s;
  __syncthreads();
  {
    int dd = t & 63;
    if (t < 192) {
      int idx = dd & 31;
      float inv = expf(-(float)idx * (1.0f / 32.0f) * 9.210340371976184f);
      float ang = (float)pos * inv;
      float sn, cs; __sincosf(ang, &sn, &cs);
      float partner = rawL[t ^ 32];
      float rot = (dd < 32) ? -partner : partner;
      float v = rawL[t] * cs + rot * sn;
      if (t < 128) qL[t >> 6][dd] = v;
      else {
        knL[dd] = v;
        if (ns == 0) out[OUT_K + (((size_t)l * B_ + b) * HKV_ + kv) * 64 + dd] = v;
      }
    } else {
      vnL[dd] = rawL[t];
      if (ns == 0) out[OUT_V + (((size_t)l * B_ + b) * HKV_ + kv) * 64 + dd] = rawL[t];
    }
  }
  __syncthreads();

  float4 q0 = *(float4*)&qL[0][4 * c];
  float4 q1 = *(float4*)&qL[1][4 * c];
  // scores: direct coalesced global K reads (predicated pos-row substitute)
  #pragma unroll
  for (int it = 0; it < 4; ++it) {
    int row = it * 16 + w * 4 + r;
    int sp = s0 + row;
    float4 k4 = (sp == pos) ? *(float4*)&knL[4 * c]
                            : *(const float4*)&Kb[(size_t)sp * 64 + 4 * c];
    float d0 = k4.x * q0.x + k4.y * q0.y + k4.z * q0.z + k4.w * q0.w;
    float d1 = k4.x * q1.x + k4.y * q1.y + k4.z * q1.z + k4.w * q1.w;
    #pragma unroll
    for (int m = 1; m <= 8; m <<= 1) { d0 += __shfl_xor(d0, m); d1 += __shfl_xor(d1, m); }
    if (c == 0) {
      bool valid = (sp <= pos);
      sc0[row] = valid ? d0 * SCALE_ : -1e30f;
      sc1[row] = valid ? d1 * SCALE_ : -1e30f;
    }
  }
  __syncthreads();
  // chunk softmax
  float v0 = (t < 64) ? sc0[t] : -1e30f;
  float v1 = (t < 64) ? sc1[t] : -1e30f;
  float m0 = wave_max(v0), m1 = wave_max(v1);
  if (lane == 0) { red[w] = m0; red[4 + w] = m1; }
  __syncthreads();
  m0 = fmaxf(fmaxf(red[0], red[1]), fmaxf(red[2], red[3]));
  m1 = fmaxf(fmaxf(red[4], red[5]), fmaxf(red[6], red[7]));
  float e0 = (t < 64) ? expf(v0 - m0) : 0.f;
  float e1 = (t < 64) ? expf(v1 - m1) : 0.f;
  __syncthreads();
  if (t < 64) { sc0[t] = e0; sc1[t] = e1; }
  float se0 = wave_sum(e0), se1 = wave_sum(e1);
  if (lane == 0) { red[w] = se0; red[4 + w] = se1; }
  __syncthreads();
  if (t == 0) {
    int base = ((b * HKV_ + kv) * 2) * NCH_ + ns;
    ws[WS_AM + base] = m0;          ws[WS_AM + base + NCH_] = m1;
    ws[WS_AL + base] = red[0] + red[1] + red[2] + red[3];
    ws[WS_AL + base + NCH_] = red[4] + red[5] + red[6] + red[7];
  }
  // PV: direct coalesced global V reads (masked rows have p=0; loads harmless)
  float4 a0 = make_float4(0.f, 0.f, 0.f, 0.f);
  float4 a1 = make_float4(0.f, 0.f, 0.f, 0.f);
  #pragma unroll
  for (int it = 0; it < 4; ++it) {
    int row = it * 16 + w * 4 + r;
    int sp = s0 + row;
    float4 v4 = (sp == pos) ? *(float4*)&vnL[4 * c]
                            : *(const float4*)&Vb[(size_t)sp * 64 + 4 * c];
    float p0 = sc0[row], p1 = sc1[row];
    a0.x += p0 * v4.x; a0.y += p0 * v4.y; a0.z += p0 * v4.z; a0.w += p0 * v4.w;
    a1.x += p1 * v4.x; a1.y += p1 * v4.y; a1.z += p1 * v4.z; a1.w += p1 * v4.w;
  }
  #pragma unroll
  for (int m = 16; m <= 32; m <<= 1) {
    a0.x += __shfl_xor(a0.x, m); a0.y += __shfl_xor(a0.y, m);
    a0.z += __shfl_xor(a0.z, m); a0.w += __shfl_xor(a0.w, m);
    a1.x += __shfl_xor(a1.x, m); a1.y += __shfl_xor(a1.y, m);
    a1.z += __shfl_xor(a1.z, m); a1.w += __shfl_xor(a1.w, m);
  }
  if (r == 0) {
    *(float4*)&oacc[0][w][4 * c] = a0;
    *(float4*)&oacc[1][w][4 * c] = a1;
  }
  __syncthreads();
  if (t < 64) {
    float r0 = oacc[0][0][t] + oacc[0][1][t] + oacc[0][2][t] + oacc[0][3][t];
    float r1 = oacc[1][0][t] + oacc[1][1][t] + oacc[1][2][t] + oacc[1][3][t];
    int h0 = kv * 2;
    ws[WS_AO + ((size_t)(b * H_ + h0)     * NCH_ + ns) * 64 + t] = r0;
    ws[WS_AO + ((size_t)(b * H_ + h0 + 1) * NCH_ + ns) * 64 + t] = r1;
  }
}

// ================= K3: o-proj GEMV, atomicAdd residual into HC ===============
// grid 128 = 4 cb x 32 kc (32 rows each)  [R9 best-measured config]
__global__ void __launch_bounds__(256)
k3_oproj(const float* __restrict__ Wo, float* __restrict__ ws, int l) {
  int cb = blockIdx.x & 3, kc = blockIdx.x >> 2;
  int t = threadIdx.x;
  int col = cb * 256 + t;
  const float* wp = Wo + ((size_t)l * HID_ + kc * 32) * HID_ + col;
  float wv[32];
  #pragma unroll
  for (int i = 0; i < 32; ++i) wv[i] = wp[(size_t)i * HID_];    // in flight

  __shared__ __align__(16) float oT[32][4];
  if (t < 128) {
    int bb = t >> 5, jj = t & 31;
    int dim = kc * 32 + jj, h = dim >> 6, d = dim & 63;
    int mb = ((bb * HKV_ + (h >> 1)) * 2 + (h & 1)) * NCH_;
    float mx = -1e30f;
    #pragma unroll
    for (int n = 0; n < NCH_; ++n) mx = fmaxf(mx, ws[WS_AM + mb + n]);
    float ls = 0.f, os = 0.f;
    #pragma unroll
    for (int n = 0; n < NCH_; ++n) {
      float wg = expf(ws[WS_AM + mb + n] - mx);
      ls += wg * ws[WS_AL + mb + n];
      os += wg * ws[WS_AO + ((size_t)(bb * H_ + h) * NCH_ + n) * 64 + d];
    }
    oT[jj][bb] = os / ls;
  }
  __syncthreads();
  float a0 = 0.f, a1 = 0.f, a2 = 0.f, a3 = 0.f;
  #pragma unroll
  for (int i = 0; i < 32; ++i) {
    float w_ = wv[i];
    float4 o4 = *(float4*)&oT[i][0];
    a0 += w_ * o4.x; a1 += w_ * o4.y; a2 += w_ * o4.z; a3 += w_ * o4.w;
  }
  atomicAdd(ws + WS_HC + 0 * HID_ + col, MUP_ * a0);
  atomicAdd(ws + WS_HC + 1 * HID_ + col, MUP_ * a1);
  atomicAdd(ws + WS_HC + 2 * HID_ + col, MUP_ * a2);
  atomicAdd(ws + WS_HC + 3 * HID_ + col, MUP_ * a3);
}

// ================= K4: gate/up GEMV (RMS prologue on HC=h2) ==================
// grid 352 = 11 cb x 32 kc (32 rows each)
__global__ void __launch_bounds__(256)
k4_gateup(const float* __restrict__ Wg, const float* __restrict__ Wu,
          const float* __restrict__ n2, float* __restrict__ ws, int l) {
  int cb = blockIdx.x % 11, kc = blockIdx.x / 11;
  int t = threadIdx.x;
  int col = cb * 256 + t;
  const float* wgp = Wg + ((size_t)l * HID_ + kc * 32) * FF_ + col;
  const float* wup = Wu + ((size_t)l * HID_ + kc * 32) * FF_ + col;
  float gv[32], uv[32];
  #pragma unroll
  for (int i = 0; i < 32; ++i) { gv[i] = wgp[(size_t)i * FF_]; uv[i] = wup[(size_t)i * FF_]; }

  const float* hsrc = ws + WS_HC;
  __shared__ float red[16];
  __shared__ __align__(16) float xs[4][32];
  float rs[4];
  rms_of(hsrc, red, rs);
  if (t < 128) {
    int b = t >> 5, i = t & 31;
    int gc = kc * 32 + i;
    xs[b][i] = hsrc[b * HID_ + gc] * rs[b] * n2[l * HID_ + gc];
  }
  __syncthreads();
  float g0 = 0.f, g1 = 0.f, g2 = 0.f, g3 = 0.f;
  float u0 = 0.f, u1 = 0.f, u2 = 0.f, u3 = 0.f;
  #pragma unroll
  for (int i = 0; i < 32; ++i) {
    float g = gv[i], u = uv[i];
    float x0 = xs[0][i], x1 = xs[1][i], x2 = xs[2][i], x3 = xs[3][i];
    g0 += g * x0; g1 += g * x1; g2 += g * x2; g3 += g * x3;
    u0 += u * x0; u1 += u * x1; u2 += u * x2; u3 += u * x3;
  }
  ws[WS_GP + ((size_t)kc * 4 + 0) * FF_ + col] = g0;
  ws[WS_GP + ((size_t)kc * 4 + 1) * FF_ + col] = g1;
  ws[WS_GP + ((size_t)kc * 4 + 2) * FF_ + col] = g2;
  ws[WS_GP + ((size_t)kc * 4 + 3) * FF_ + col] = g3;
  ws[WS_UP + ((size_t)kc * 4 + 0) * FF_ + col] = u0;
  ws[WS_UP + ((size_t)kc * 4 + 1) * FF_ + col] = u1;
  ws[WS_UP + ((size_t)kc * 4 + 2) * FF_ + col] = u2;
  ws[WS_UP + ((size_t)kc * 4 + 3) * FF_ + col] = u3;
}

// ================= K5: down GEMV (silu-combine), atomicAdd into HC ===========
// grid 176 = 4 cb x 44 kc (64 rows each)  [R9 best-measured config]
__global__ void __launch_bounds__(256)
k5_down(const float* __restrict__ Wd, float* __restrict__ ws, int l) {
  int cb = blockIdx.x & 3, kc = blockIdx.x >> 2;   // kc<44
  int t = threadIdx.x;
  int col = cb * 256 + t;
  const float* wp = Wd + ((size_t)l * FF_ + kc * 64) * HID_ + col;
  float wv[64];
  #pragma unroll
  for (int i = 0; i < 64; ++i) wv[i] = wp[(size_t)i * HID_];    // in flight

  __shared__ __align__(16) float mT[64][4];
  {
    int bb = t >> 6, jj = t & 63;       // 256 items = 64 rows x 4 batches
    int f = kc * 64 + jj;
    float g = 0.f, u = 0.f;
    #pragma unroll
    for (int k2 = 0; k2 < 32; ++k2) {
      g += ws[WS_GP + ((size_t)k2 * 4 + bb) * FF_ + f];
      u += ws[WS_UP + ((size_t)k2 * 4 + bb) * FF_ + f];
    }
    float sig = 1.f / (1.f + expf(-g));
    mT[jj][bb] = g * sig * u;
  }
  __syncthreads();
  float a0 = 0.f, a1 = 0.f, a2 = 0.f, a3 = 0.f;
  #pragma unroll
  for (int i = 0; i < 64; ++i) {
    float w_ = wv[i];
    float4 m4 = *(float4*)&mT[i][0];
    a0 += w_ * m4.x; a1 += w_ * m4.y; a2 += w_ * m4.z; a3 += w_ * m4.w;
  }
  atomicAdd(ws + WS_HC + 0 * HID_ + col, MUP_ * a0);
  atomicAdd(ws + WS_HC + 1 * HID_ + col, MUP_ * a1);
  atomicAdd(ws + WS_HC + 2 * HID_ + col, MUP_ * a2);
  atomicAdd(ws + WS_HC + 3 * HID_ + col, MUP_ * a3);
}

// ================= K6: final RMS(HC)*fw -> out, plus pos+1 ===================
__global__ void __launch_bounds__(256)
k6_final(const float* __restrict__ fw, const int* __restrict__ posp,
         float* __restrict__ ws, float* __restrict__ out) {
  int b = blockIdx.x, t = threadIdx.x;
  __shared__ float red[4];
  float hv[4];
  float part = 0.f;
  for (int j = 0; j < 4; ++j) {
    float v = ws[WS_HC + b * HID_ + t + j * 256];
    hv[j] = v; part += v * v;
  }
  part = wave_sum(part);
  if ((t & 63) == 0) red[t >> 6] = part;
  __syncthreads();
  float rs = rsqrtf((red[0] + red[1] + red[2] + red[3]) * (1.0f / HID_) + EPS_);
  for (int j = 0; j < 4; ++j) {
    int c2 = t + j * 256;
    out[OUT_H + b * HID_ + c2] = hv[j] * rs * fw[c2];
  }
  if (b == 0 && t == 0) out[OUT_POS] = (float)(read_pos_dev(posp) + 1);
}

extern "C" void kernel_launch(void* const* d_in, const int* in_sizes, int n_in,
                              void* d_out, int out_size, void* d_ws, size_t ws_size,
                              hipStream_t stream) {
  const float* x   = (const float*)d_in[0];
  const float* kcp = (const float*)d_in[1];
  const float* vcp = (const float*)d_in[2];
  const float* Wq  = (const float*)d_in[3];
  const float* Wk  = (const float*)d_in[4];
  const float* Wv  = (const float*)d_in[5];
  const float* Wo  = (const float*)d_in[6];
  const float* Wg  = (const float*)d_in[7];
  const float* Wu  = (const float*)d_in[8];
  const float* Wd  = (const float*)d_in[9];
  const float* n1  = (const float*)d_in[10];
  const float* n2  = (const float*)d_in[11];
  const float* fw  = (const float*)d_in[12];
  const int*   pos = (const int*)d_in[13];
  float* ws  = (float*)d_ws;
  float* out = (float*)d_out;

  for (int l = 0; l < L_; ++l) {
    k1_qkv   <<< 256, 256, 0, stream>>>(Wq, Wk, Wv, n1, x, ws, l);
    k2_attn  <<<1024, 256, 0, stream>>>(kcp, vcp, pos, ws, out, l);
    k3_oproj <<< 128, 256, 0, stream>>>(Wo, ws, l);
    k4_gateup<<< 352, 256, 0, stream>>>(Wg, Wu, n2, ws, l);
    k5_down  <<< 176, 256, 0, stream>>>(Wd, ws, l);
  }
  k6_final<<<4, 256, 0, stream>>>(fw, pos, ws, out);
}

// Round 14
// 287.222 us; speedup vs baseline: 3.8492x; 1.0459x over previous
//
#include <hip/hip_runtime.h>

// MiniCPM-style decode step: L=8 B=4 H=16 HKV=8 D=64 S=2048 HID=1024 FF=2816
#define L_   8
#define B_   4
#define H_   16
#define HKV_ 8
#define D_   64
#define S_   2048
#define HID_ 1024
#define FF_  2816
#define EPS_ 1e-5f
#define MUP_ 0.49497474683058327f   // 1.4/sqrt(8)
#define SCALE_ 0.125f               // 1/sqrt(64)
#define NCH_ 32                     // attention chunks of 64 positions

// d_out is FLOAT32: [h 4096 | k_upd 16384 | v_upd 16384 | pos+1]
#define OUT_H   0
#define OUT_K   4096
#define OUT_V   (4096 + 16384)
#define OUT_POS (4096 + 16384 + 16384)

// ---------------- workspace layout (floats) ----------------
// QA/GA/UA are cross-kernel atomic accumulators ([b][col]); zeroed in-pipeline:
//   QA: written by k1 (atomicAdd), read by k2, zeroed by k3 (for next layer).
//   GA/UA: written by k4, read by k5, zeroed by k2 blocks 0-87 (before k4).
enum {
  WS_HC  = 0,                        // 4096   live hidden state (atomics)
  WS_QA  = 4096,                     // 8192   [b][col<2048]
  WS_AM  = 12288,                    // 2048   [b][kv][2][32]
  WS_AL  = 14336,                    // 2048
  WS_AO  = 16384,                    // 131072 [b][h][ns][d]
  WS_GA  = 147456,                   // 11264  [b][col<2816]
  WS_UA  = 158720,                   // 11264
  WS_END = 169984                    // ~680 KB
};

__device__ __forceinline__ int read_pos_dev(const int* p) {
  int v = p[0];
  if (v >= 0 && v < S_) return v;
  float f = __int_as_float(v);
  if (f >= 0.0f && f <= (float)(S_ - 1)) return (int)(f + 0.5f);
  return 1500;
}

__device__ __forceinline__ float wave_sum(float v) {
  for (int m = 1; m < 64; m <<= 1) v += __shfl_xor(v, m);
  return v;
}
__device__ __forceinline__ float wave_max(float v) {
  for (int m = 1; m < 64; m <<= 1) v = fmaxf(v, __shfl_xor(v, m));
  return v;
}

// shared RMS prologue: read 4x1024 h, per-batch rsqrt(mean sq)
__device__ __forceinline__ void rms_of(const float* hsrc, float* red, float* rs) {
  int t = threadIdx.x;
  float part[4] = {0.f, 0.f, 0.f, 0.f};
  #pragma unroll
  for (int j = 0; j < 4; ++j) {
    int c2 = t + j * 256;
    #pragma unroll
    for (int b = 0; b < 4; ++b) {
      float v = hsrc[b * HID_ + c2];
      part[b] += v * v;
    }
  }
  int w = t >> 6;
  #pragma unroll
  for (int b = 0; b < 4; ++b) {
    float s = wave_sum(part[b]);
    if ((t & 63) == 0) red[w * 4 + b] = s;
  }
  __syncthreads();
  #pragma unroll
  for (int b = 0; b < 4; ++b)
    rs[b] = rsqrtf((red[b] + red[4 + b] + red[8 + b] + red[12 + b]) * (1.0f / HID_) + EPS_);
}

// ================= K1: QKV GEMV -> atomicAdd into QA =================
// grid 256 = 8 cb x 32 kc (32 rows each)
__global__ void __launch_bounds__(256)
k1_qkv(const float* __restrict__ Wq, const float* __restrict__ Wk,
       const float* __restrict__ Wv, const float* __restrict__ n1,
       const float* __restrict__ x, float* __restrict__ ws, int l) {
  int cb = blockIdx.x & 7, kc = blockIdx.x >> 3;
  int t = threadIdx.x;
  int col = cb * 256 + t;
  const float* W; int wcol, stride;
  if (col < 1024)      { W = Wq + (size_t)l * HID_ * 1024; wcol = col;        stride = 1024; }
  else if (col < 1536) { W = Wk + (size_t)l * HID_ * 512;  wcol = col - 1024; stride = 512;  }
  else                 { W = Wv + (size_t)l * HID_ * 512;  wcol = col - 1536; stride = 512;  }
  const float* wp = W + (size_t)(kc * 32) * stride + wcol;
  float wv[32];
  #pragma unroll
  for (int i = 0; i < 32; ++i) wv[i] = wp[(size_t)i * stride];   // in flight

  const float* hsrc = (l == 0) ? x : (ws + WS_HC);
  __shared__ float red[16];
  __shared__ __align__(16) float xs[4][32];
  float rs[4];
  rms_of(hsrc, red, rs);
  if (l == 0 && blockIdx.x < 4) {        // seed HC = x (blocks 0-3, one batch each)
    for (int j = 0; j < 4; ++j) {
      int c2 = t + j * 256;
      ws[WS_HC + blockIdx.x * HID_ + c2] = x[blockIdx.x * HID_ + c2];
    }
  }
  if (t < 128) {
    int b = t >> 5, i = t & 31;
    int gc = kc * 32 + i;
    xs[b][i] = hsrc[b * HID_ + gc] * rs[b] * n1[l * HID_ + gc];
  }
  __syncthreads();
  float a0 = 0.f, a1 = 0.f, a2 = 0.f, a3 = 0.f;
  #pragma unroll
  for (int i = 0; i < 32; ++i) {
    float w_ = wv[i];
    a0 += w_ * xs[0][i]; a1 += w_ * xs[1][i];
    a2 += w_ * xs[2][i]; a3 += w_ * xs[3][i];
  }
  atomicAdd(ws + WS_QA + 0 * 2048 + col, a0);
  atomicAdd(ws + WS_QA + 1 * 2048 + col, a1);
  atomicAdd(ws + WS_QA + 2 * 2048 + col, a2);
  atomicAdd(ws + WS_QA + 3 * 2048 + col, a3);
}

// ================= K2: qkv read + rope + kv-out + flash chunk (direct loads) ==
// grid 1024 = (b,kv) x 32 chunks of 64 positions; fully-masked chunks skip.
// Blocks 0-87 also zero GA/UA for this layer's k4 (placed before early-exit).
__global__ void __launch_bounds__(256)
k2_attn(const float* __restrict__ kcache, const float* __restrict__ vcache,
        const int* __restrict__ posp, float* __restrict__ ws,
        float* __restrict__ out, int l) {
  int bh = blockIdx.x >> 5, ns = blockIdx.x & 31;
  int b = bh >> 3, kv = bh & 7;
  int t = threadIdx.x;
  int w = t >> 6, lane = t & 63, r = lane >> 4, c = lane & 15;
  int pos = read_pos_dev(posp);
  int s0 = ns * 64;

  if (blockIdx.x < 88) {               // zero GA/UA (22528 floats over 88 blocks)
    int i = blockIdx.x * 256 + t;      // 0..22527
    ws[WS_GA + i] = 0.f;               // covers GA then UA (contiguous regions)
  }

  if (s0 > pos) {                      // fully-masked chunk: sentinels, no traffic
    if (t == 0) {
      int base = ((b * HKV_ + kv) * 2) * NCH_ + ns;
      ws[WS_AM + base] = -1e30f;       ws[WS_AM + base + NCH_] = -1e30f;
      ws[WS_AL + base] = 0.f;          ws[WS_AL + base + NCH_] = 0.f;
    }
    return;
  }
  __shared__ __align__(16) float qL[2][64];
  __shared__ __align__(16) float knL[64], vnL[64];
  __shared__ float rawL[256], sc0[64], sc1[64], red[8];
  __shared__ __align__(16) float oacc[2][4][64];

  const float* Kb = kcache + (((size_t)l * B_ + b) * HKV_ + kv) * S_ * 64;
  const float* Vb = vcache + (((size_t)l * B_ + b) * HKV_ + kv) * S_ * 64;

  // read combined qkv from QA; rope
  int cg;
  if (t < 128)      cg = (kv * 2 + (t >> 6)) * 64 + (t & 63);
  else if (t < 192) cg = 1024 + kv * 64 + (t & 63);
  else              cg = 1536 + kv * 64 + (t & 63);
  rawL[t] = ws[WS_QA + b * 2048 + cg];
  __syncthreads();
  {
    int dd = t & 63;
    if (t < 192) {
      int idx = dd & 31;
      float inv = expf(-(float)idx * (1.0f / 32.0f) * 9.210340371976184f);
      float ang = (float)pos * inv;
      float sn, cs; __sincosf(ang, &sn, &cs);
      float partner = rawL[t ^ 32];
      float rot = (dd < 32) ? -partner : partner;
      float v = rawL[t] * cs + rot * sn;
      if (t < 128) qL[t >> 6][dd] = v;
      else {
        knL[dd] = v;
        if (ns == 0) out[OUT_K + (((size_t)l * B_ + b) * HKV_ + kv) * 64 + dd] = v;
      }
    } else {
      vnL[dd] = rawL[t];
      if (ns == 0) out[OUT_V + (((size_t)l * B_ + b) * HKV_ + kv) * 64 + dd] = rawL[t];
    }
  }
  __syncthreads();

  float4 q0 = *(float4*)&qL[0][4 * c];
  float4 q1 = *(float4*)&qL[1][4 * c];
  // scores: direct coalesced global K reads (predicated pos-row substitute)
  #pragma unroll
  for (int it = 0; it < 4; ++it) {
    int row = it * 16 + w * 4 + r;
    int sp = s0 + row;
    float4 k4 = (sp == pos) ? *(float4*)&knL[4 * c]
                            : *(const float4*)&Kb[(size_t)sp * 64 + 4 * c];
    float d0 = k4.x * q0.x + k4.y * q0.y + k4.z * q0.z + k4.w * q0.w;
    float d1 = k4.x * q1.x + k4.y * q1.y + k4.z * q1.z + k4.w * q1.w;
    #pragma unroll
    for (int m = 1; m <= 8; m <<= 1) { d0 += __shfl_xor(d0, m); d1 += __shfl_xor(d1, m); }
    if (c == 0) {
      bool valid = (sp <= pos);
      sc0[row] = valid ? d0 * SCALE_ : -1e30f;
      sc1[row] = valid ? d1 * SCALE_ : -1e30f;
    }
  }
  __syncthreads();
  // chunk softmax
  float v0 = (t < 64) ? sc0[t] : -1e30f;
  float v1 = (t < 64) ? sc1[t] : -1e30f;
  float m0 = wave_max(v0), m1 = wave_max(v1);
  if (lane == 0) { red[w] = m0; red[4 + w] = m1; }
  __syncthreads();
  m0 = fmaxf(fmaxf(red[0], red[1]), fmaxf(red[2], red[3]));
  m1 = fmaxf(fmaxf(red[4], red[5]), fmaxf(red[6], red[7]));
  float e0 = (t < 64) ? expf(v0 - m0) : 0.f;
  float e1 = (t < 64) ? expf(v1 - m1) : 0.f;
  __syncthreads();
  if (t < 64) { sc0[t] = e0; sc1[t] = e1; }
  float se0 = wave_sum(e0), se1 = wave_sum(e1);
  if (lane == 0) { red[w] = se0; red[4 + w] = se1; }
  __syncthreads();
  if (t == 0) {
    int base = ((b * HKV_ + kv) * 2) * NCH_ + ns;
    ws[WS_AM + base] = m0;          ws[WS_AM + base + NCH_] = m1;
    ws[WS_AL + base] = red[0] + red[1] + red[2] + red[3];
    ws[WS_AL + base + NCH_] = red[4] + red[5] + red[6] + red[7];
  }
  // PV: direct coalesced global V reads
  float4 a0 = make_float4(0.f, 0.f, 0.f, 0.f);
  float4 a1 = make_float4(0.f, 0.f, 0.f, 0.f);
  #pragma unroll
  for (int it = 0; it < 4; ++it) {
    int row = it * 16 + w * 4 + r;
    int sp = s0 + row;
    float4 v4 = (sp == pos) ? *(float4*)&vnL[4 * c]
                            : *(const float4*)&Vb[(size_t)sp * 64 + 4 * c];
    float p0 = sc0[row], p1 = sc1[row];
    a0.x += p0 * v4.x; a0.y += p0 * v4.y; a0.z += p0 * v4.z; a0.w += p0 * v4.w;
    a1.x += p1 * v4.x; a1.y += p1 * v4.y; a1.z += p1 * v4.z; a1.w += p1 * v4.w;
  }
  #pragma unroll
  for (int m = 16; m <= 32; m <<= 1) {
    a0.x += __shfl_xor(a0.x, m); a0.y += __shfl_xor(a0.y, m);
    a0.z += __shfl_xor(a0.z, m); a0.w += __shfl_xor(a0.w, m);
    a1.x += __shfl_xor(a1.x, m); a1.y += __shfl_xor(a1.y, m);
    a1.z += __shfl_xor(a1.z, m); a1.w += __shfl_xor(a1.w, m);
  }
  if (r == 0) {
    *(float4*)&oacc[0][w][4 * c] = a0;
    *(float4*)&oacc[1][w][4 * c] = a1;
  }
  __syncthreads();
  if (t < 64) {
    float r0 = oacc[0][0][t] + oacc[0][1][t] + oacc[0][2][t] + oacc[0][3][t];
    float r1 = oacc[1][0][t] + oacc[1][1][t] + oacc[1][2][t] + oacc[1][3][t];
    int h0 = kv * 2;
    ws[WS_AO + ((size_t)(b * H_ + h0)     * NCH_ + ns) * 64 + t] = r0;
    ws[WS_AO + ((size_t)(b * H_ + h0 + 1) * NCH_ + ns) * 64 + t] = r1;
  }
}

// ================= K3: o-proj GEMV, atomicAdd residual into HC; zero QA ======
// grid 128 = 4 cb x 32 kc (32 rows each)
__global__ void __launch_bounds__(256)
k3_oproj(const float* __restrict__ Wo, float* __restrict__ ws, int l) {
  int cb = blockIdx.x & 3, kc = blockIdx.x >> 2;
  int t = threadIdx.x;
  int col = cb * 256 + t;
  const float* wp = Wo + ((size_t)l * HID_ + kc * 32) * HID_ + col;
  float wv[32];
  #pragma unroll
  for (int i = 0; i < 32; ++i) wv[i] = wp[(size_t)i * HID_];    // in flight

  if (blockIdx.x < 32) {       // zero QA (8192 floats) for next layer's k1
    ws[WS_QA + blockIdx.x * 256 + t] = 0.f;
  }

  __shared__ __align__(16) float oT[32][4];
  if (t < 128) {
    int bb = t >> 5, jj = t & 31;
    int dim = kc * 32 + jj, h = dim >> 6, d = dim & 63;
    int mb = ((bb * HKV_ + (h >> 1)) * 2 + (h & 1)) * NCH_;
    float mx = -1e30f;
    #pragma unroll
    for (int n = 0; n < NCH_; ++n) mx = fmaxf(mx, ws[WS_AM + mb + n]);
    float ls = 0.f, os = 0.f;
    #pragma unroll
    for (int n = 0; n < NCH_; ++n) {
      float wg = expf(ws[WS_AM + mb + n] - mx);
      ls += wg * ws[WS_AL + mb + n];
      os += wg * ws[WS_AO + ((size_t)(bb * H_ + h) * NCH_ + n) * 64 + d];
    }
    oT[jj][bb] = os / ls;
  }
  __syncthreads();
  float a0 = 0.f, a1 = 0.f, a2 = 0.f, a3 = 0.f;
  #pragma unroll
  for (int i = 0; i < 32; ++i) {
    float w_ = wv[i];
    float4 o4 = *(float4*)&oT[i][0];
    a0 += w_ * o4.x; a1 += w_ * o4.y; a2 += w_ * o4.z; a3 += w_ * o4.w;
  }
  atomicAdd(ws + WS_HC + 0 * HID_ + col, MUP_ * a0);
  atomicAdd(ws + WS_HC + 1 * HID_ + col, MUP_ * a1);
  atomicAdd(ws + WS_HC + 2 * HID_ + col, MUP_ * a2);
  atomicAdd(ws + WS_HC + 3 * HID_ + col, MUP_ * a3);
}

// ================= K4: gate/up GEMV (RMS on HC) -> atomicAdd GA/UA ===========
// grid 352 = 11 cb x 32 kc (32 rows each)
__global__ void __launch_bounds__(256)
k4_gateup(const float* __restrict__ Wg, const float* __restrict__ Wu,
          const float* __restrict__ n2, float* __restrict__ ws, int l) {
  int cb = blockIdx.x % 11, kc = blockIdx.x / 11;
  int t = threadIdx.x;
  int col = cb * 256 + t;
  const float* wgp = Wg + ((size_t)l * HID_ + kc * 32) * FF_ + col;
  const float* wup = Wu + ((size_t)l * HID_ + kc * 32) * FF_ + col;
  float gv[32], uv[32];
  #pragma unroll
  for (int i = 0; i < 32; ++i) { gv[i] = wgp[(size_t)i * FF_]; uv[i] = wup[(size_t)i * FF_]; }

  const float* hsrc = ws + WS_HC;
  __shared__ float red[16];
  __shared__ __align__(16) float xs[4][32];
  float rs[4];
  rms_of(hsrc, red, rs);
  if (t < 128) {
    int b = t >> 5, i = t & 31;
    int gc = kc * 32 + i;
    xs[b][i] = hsrc[b * HID_ + gc] * rs[b] * n2[l * HID_ + gc];
  }
  __syncthreads();
  float g0 = 0.f, g1 = 0.f, g2 = 0.f, g3 = 0.f;
  float u0 = 0.f, u1 = 0.f, u2 = 0.f, u3 = 0.f;
  #pragma unroll
  for (int i = 0; i < 32; ++i) {
    float g = gv[i], u = uv[i];
    float x0 = xs[0][i], x1 = xs[1][i], x2 = xs[2][i], x3 = xs[3][i];
    g0 += g * x0; g1 += g * x1; g2 += g * x2; g3 += g * x3;
    u0 += u * x0; u1 += u * x1; u2 += u * x2; u3 += u * x3;
  }
  atomicAdd(ws + WS_GA + 0 * FF_ + col, g0);
  atomicAdd(ws + WS_GA + 1 * FF_ + col, g1);
  atomicAdd(ws + WS_GA + 2 * FF_ + col, g2);
  atomicAdd(ws + WS_GA + 3 * FF_ + col, g3);
  atomicAdd(ws + WS_UA + 0 * FF_ + col, u0);
  atomicAdd(ws + WS_UA + 1 * FF_ + col, u1);
  atomicAdd(ws + WS_UA + 2 * FF_ + col, u2);
  atomicAdd(ws + WS_UA + 3 * FF_ + col, u3);
}

// ================= K5: down GEMV (silu from GA/UA), atomicAdd into HC ========
// grid 176 = 4 cb x 44 kc (64 rows each)
__global__ void __launch_bounds__(256)
k5_down(const float* __restrict__ Wd, float* __restrict__ ws, int l) {
  int cb = blockIdx.x & 3, kc = blockIdx.x >> 2;   // kc<44
  int t = threadIdx.x;
  int col = cb * 256 + t;
  const float* wp = Wd + ((size_t)l * FF_ + kc * 64) * HID_ + col;
  float wv[64];
  #pragma unroll
  for (int i = 0; i < 64; ++i) wv[i] = wp[(size_t)i * HID_];    // in flight

  __shared__ __align__(16) float mT[64][4];
  {
    int bb = t >> 6, jj = t & 63;       // 256 items = 64 rows x 4 batches
    int f = kc * 64 + jj;
    float g = ws[WS_GA + bb * FF_ + f];
    float u = ws[WS_UA + bb * FF_ + f];
    float sig = 1.f / (1.f + expf(-g));
    mT[jj][bb] = g * sig * u;
  }
  __syncthreads();
  float a0 = 0.f, a1 = 0.f, a2 = 0.f, a3 = 0.f;
  #pragma unroll
  for (int i = 0; i < 64; ++i) {
    float w_ = wv[i];
    float4 m4 = *(float4*)&mT[i][0];
    a0 += w_ * m4.x; a1 += w_ * m4.y; a2 += w_ * m4.z; a3 += w_ * m4.w;
  }
  atomicAdd(ws + WS_HC + 0 * HID_ + col, MUP_ * a0);
  atomicAdd(ws + WS_HC + 1 * HID_ + col, MUP_ * a1);
  atomicAdd(ws + WS_HC + 2 * HID_ + col, MUP_ * a2);
  atomicAdd(ws + WS_HC + 3 * HID_ + col, MUP_ * a3);
}

// ================= K6: final RMS(HC)*fw -> out, plus pos+1 ===================
__global__ void __launch_bounds__(256)
k6_final(const float* __restrict__ fw, const int* __restrict__ posp,
         float* __restrict__ ws, float* __restrict__ out) {
  int b = blockIdx.x, t = threadIdx.x;
  __shared__ float red[4];
  float hv[4];
  float part = 0.f;
  for (int j = 0; j < 4; ++j) {
    float v = ws[WS_HC + b * HID_ + t + j * 256];
    hv[j] = v; part += v * v;
  }
  part = wave_sum(part);
  if ((t & 63) == 0) red[t >> 6] = part;
  __syncthreads();
  float rs = rsqrtf((red[0] + red[1] + red[2] + red[3]) * (1.0f / HID_) + EPS_);
  for (int j = 0; j < 4; ++j) {
    int c2 = t + j * 256;
    out[OUT_H + b * HID_ + c2] = hv[j] * rs * fw[c2];
  }
  if (b == 0 && t == 0) out[OUT_POS] = (float)(read_pos_dev(posp) + 1);
}

extern "C" void kernel_launch(void* const* d_in, const int* in_sizes, int n_in,
                              void* d_out, int out_size, void* d_ws, size_t ws_size,
                              hipStream_t stream) {
  const float* x   = (const float*)d_in[0];
  const float* kcp = (const float*)d_in[1];
  const float* vcp = (const float*)d_in[2];
  const float* Wq  = (const float*)d_in[3];
  const float* Wk  = (const float*)d_in[4];
  const float* Wv  = (const float*)d_in[5];
  const float* Wo  = (const float*)d_in[6];
  const float* Wg  = (const float*)d_in[7];
  const float* Wu  = (const float*)d_in[8];
  const float* Wd  = (const float*)d_in[9];
  const float* n1  = (const float*)d_in[10];
  const float* n2  = (const float*)d_in[11];
  const float* fw  = (const float*)d_in[12];
  const int*   pos = (const int*)d_in[13];
  float* ws  = (float*)d_ws;
  float* out = (float*)d_out;

  // seed QA = 0 for layer 0 (k3 re-zeroes it each layer thereafter)
  hipMemsetAsync(ws + WS_QA, 0, 8192 * sizeof(float), stream);

  for (int l = 0; l < L_; ++l) {
    k1_qkv   <<< 256, 256, 0, stream>>>(Wq, Wk, Wv, n1, x, ws, l);
    k2_attn  <<<1024, 256, 0, stream>>>(kcp, vcp, pos, ws, out, l);
    k3_oproj <<< 128, 256, 0, stream>>>(Wo, ws, l);
    k4_gateup<<< 352, 256, 0, stream>>>(Wg, Wu, n2, ws, l);
    k5_down  <<< 176, 256, 0, stream>>>(Wd, ws, l);
  }
  k6_final<<<4, 256, 0, stream>>>(fw, pos, ws, out);
}

// Round 15
// 285.002 us; speedup vs baseline: 3.8792x; 1.0078x over previous
//
#include <hip/hip_runtime.h>

// MiniCPM-style decode step: L=8 B=4 H=16 HKV=8 D=64 S=2048 HID=1024 FF=2816
#define L_   8
#define B_   4
#define H_   16
#define HKV_ 8
#define D_   64
#define S_   2048
#define HID_ 1024
#define FF_  2816
#define EPS_ 1e-5f
#define MUP_ 0.49497474683058327f   // 1.4/sqrt(8)
#define SCALE_ 0.125f               // 1/sqrt(64)
#define NCH_ 32                     // attention chunks of 64 positions

// d_out is FLOAT32: [h 4096 | k_upd 16384 | v_upd 16384 | pos+1]
#define OUT_H   0
#define OUT_K   4096
#define OUT_V   (4096 + 16384)
#define OUT_POS (4096 + 16384 + 16384)

// ---------------- workspace layout (floats) ----------------
enum {
  WS_HC  = 0,                        // 4096   live hidden state (atomics)
  WS_QA  = 4096,                     // 8192   [b][col<2048]
  WS_AM  = 12288,                    // 2048   [b][kv][2][32]
  WS_AL  = 14336,                    // 2048
  WS_AO  = 16384,                    // 131072 [b][h][ns][d]
  WS_GA  = 147456,                   // 11264  [b][col<2816]
  WS_UA  = 158720,                   // 11264
  WS_END = 169984                    // ~680 KB
};

__device__ __forceinline__ int read_pos_dev(const int* p) {
  int v = p[0];
  if (v >= 0 && v < S_) return v;
  float f = __int_as_float(v);
  if (f >= 0.0f && f <= (float)(S_ - 1)) return (int)(f + 0.5f);
  return 1500;
}

__device__ __forceinline__ float wave_sum(float v) {
  for (int m = 1; m < 64; m <<= 1) v += __shfl_xor(v, m);
  return v;
}
__device__ __forceinline__ float wave_max(float v) {
  for (int m = 1; m < 64; m <<= 1) v = fmaxf(v, __shfl_xor(v, m));
  return v;
}

// shared RMS prologue: read 4x1024 h, per-batch rsqrt(mean sq)
__device__ __forceinline__ void rms_of(const float* hsrc, float* red, float* rs) {
  int t = threadIdx.x;
  float part[4] = {0.f, 0.f, 0.f, 0.f};
  #pragma unroll
  for (int j = 0; j < 4; ++j) {
    int c2 = t + j * 256;
    #pragma unroll
    for (int b = 0; b < 4; ++b) {
      float v = hsrc[b * HID_ + c2];
      part[b] += v * v;
    }
  }
  int w = t >> 6;
  #pragma unroll
  for (int b = 0; b < 4; ++b) {
    float s = wave_sum(part[b]);
    if ((t & 63) == 0) red[w * 4 + b] = s;
  }
  __syncthreads();
  #pragma unroll
  for (int b = 0; b < 4; ++b)
    rs[b] = rsqrtf((red[b] + red[4 + b] + red[8 + b] + red[12 + b]) * (1.0f / HID_) + EPS_);
}

// ================= K1: QKV GEMV -> atomicAdd into QA =================
// grid 256 = 8 cb x 32 kc (32 rows each)
__global__ void __launch_bounds__(256)
k1_qkv(const float* __restrict__ Wq, const float* __restrict__ Wk,
       const float* __restrict__ Wv, const float* __restrict__ n1,
       const float* __restrict__ x, float* __restrict__ ws, int l) {
  int cb = blockIdx.x & 7, kc = blockIdx.x >> 3;
  int t = threadIdx.x;
  int col = cb * 256 + t;
  const float* W; int wcol, stride;
  if (col < 1024)      { W = Wq + (size_t)l * HID_ * 1024; wcol = col;        stride = 1024; }
  else if (col < 1536) { W = Wk + (size_t)l * HID_ * 512;  wcol = col - 1024; stride = 512;  }
  else                 { W = Wv + (size_t)l * HID_ * 512;  wcol = col - 1536; stride = 512;  }
  const float* wp = W + (size_t)(kc * 32) * stride + wcol;
  float wv[32];
  #pragma unroll
  for (int i = 0; i < 32; ++i) wv[i] = wp[(size_t)i * stride];   // in flight

  const float* hsrc = (l == 0) ? x : (ws + WS_HC);
  __shared__ float red[16];
  __shared__ __align__(16) float xs[4][32];
  float rs[4];
  rms_of(hsrc, red, rs);
  if (l == 0 && blockIdx.x < 4) {        // seed HC = x (blocks 0-3, one batch each)
    for (int j = 0; j < 4; ++j) {
      int c2 = t + j * 256;
      ws[WS_HC + blockIdx.x * HID_ + c2] = x[blockIdx.x * HID_ + c2];
    }
  }
  if (t < 128) {
    int b = t >> 5, i = t & 31;
    int gc = kc * 32 + i;
    xs[b][i] = hsrc[b * HID_ + gc] * rs[b] * n1[l * HID_ + gc];
  }
  __syncthreads();
  float a0 = 0.f, a1 = 0.f, a2 = 0.f, a3 = 0.f;
  #pragma unroll
  for (int i = 0; i < 32; ++i) {
    float w_ = wv[i];
    a0 += w_ * xs[0][i]; a1 += w_ * xs[1][i];
    a2 += w_ * xs[2][i]; a3 += w_ * xs[3][i];
  }
  atomicAdd(ws + WS_QA + 0 * 2048 + col, a0);
  atomicAdd(ws + WS_QA + 1 * 2048 + col, a1);
  atomicAdd(ws + WS_QA + 2 * 2048 + col, a2);
  atomicAdd(ws + WS_QA + 3 * 2048 + col, a3);
}

// ================= K2: qkv read + rope + kv-out + flash chunk ==============
// grid 1024 = (b,kv) x 32 chunks of 64 positions; fully-masked chunks skip.
// KV chunk hoisted into registers at kernel top (after 1 QA scalar load) so
// the 24MB/layer KV stream bursts early and overlaps the rope/softmax phases.
// Blocks 0-87 also zero GA/UA for this layer's k4 (before early-exit).
__global__ void __launch_bounds__(256)
k2_attn(const float* __restrict__ kcache, const float* __restrict__ vcache,
        const int* __restrict__ posp, float* __restrict__ ws,
        float* __restrict__ out, int l) {
  int bh = blockIdx.x >> 5, ns = blockIdx.x & 31;
  int b = bh >> 3, kv = bh & 7;
  int t = threadIdx.x;
  int w = t >> 6, lane = t & 63, r = lane >> 4, c = lane & 15;
  int pos = read_pos_dev(posp);
  int s0 = ns * 64;

  if (blockIdx.x < 88) {               // zero GA/UA (22528 floats over 88 blocks)
    int i = blockIdx.x * 256 + t;
    ws[WS_GA + i] = 0.f;
  }

  if (s0 > pos) {                      // fully-masked chunk: sentinels, no traffic
    if (t == 0) {
      int base = ((b * HKV_ + kv) * 2) * NCH_ + ns;
      ws[WS_AM + base] = -1e30f;       ws[WS_AM + base + NCH_] = -1e30f;
      ws[WS_AL + base] = 0.f;          ws[WS_AL + base + NCH_] = 0.f;
    }
    return;
  }

  // issue QA scalar load FIRST (so its wait doesn't drain the KV stream)
  int cg;
  if (t < 128)      cg = (kv * 2 + (t >> 6)) * 64 + (t & 63);
  else if (t < 192) cg = 1024 + kv * 64 + (t & 63);
  else              cg = 1536 + kv * 64 + (t & 63);
  float qa = ws[WS_QA + b * 2048 + cg];

  // hoist the full KV chunk into registers (8 x float4 per thread, in flight)
  const float* Kb = kcache + (((size_t)l * B_ + b) * HKV_ + kv) * S_ * 64;
  const float* Vb = vcache + (((size_t)l * B_ + b) * HKV_ + kv) * S_ * 64;
  float4 kr[4], vr[4];
  #pragma unroll
  for (int it = 0; it < 4; ++it) {
    int row = it * 16 + w * 4 + r;
    int sp = s0 + row;
    kr[it] = *(const float4*)&Kb[(size_t)sp * 64 + 4 * c];
    vr[it] = *(const float4*)&Vb[(size_t)sp * 64 + 4 * c];
  }

  __shared__ __align__(16) float qL[2][64];
  __shared__ __align__(16) float knL[64], vnL[64];
  __shared__ float rawL[256], sc0[64], sc1[64], red[8];
  __shared__ __align__(16) float oacc[2][4][64];

  rawL[t] = qa;                        // waits only on the QA load
  __syncthreads();
  {
    int dd = t & 63;
    if (t < 192) {
      int idx = dd & 31;
      float inv = expf(-(float)idx * (1.0f / 32.0f) * 9.210340371976184f);
      float ang = (float)pos * inv;
      float sn, cs; __sincosf(ang, &sn, &cs);
      float partner = rawL[t ^ 32];
      float rot = (dd < 32) ? -partner : partner;
      float v = rawL[t] * cs + rot * sn;
      if (t < 128) qL[t >> 6][dd] = v;
      else {
        knL[dd] = v;
        if (ns == 0) out[OUT_K + (((size_t)l * B_ + b) * HKV_ + kv) * 64 + dd] = v;
      }
    } else {
      vnL[dd] = rawL[t];
      if (ns == 0) out[OUT_V + (((size_t)l * B_ + b) * HKV_ + kv) * 64 + dd] = rawL[t];
    }
  }
  __syncthreads();

  float4 q0 = *(float4*)&qL[0][4 * c];
  float4 q1 = *(float4*)&qL[1][4 * c];
  // scores from registers (predicated pos-row substitute)
  #pragma unroll
  for (int it = 0; it < 4; ++it) {
    int row = it * 16 + w * 4 + r;
    int sp = s0 + row;
    float4 k4 = (sp == pos) ? *(float4*)&knL[4 * c] : kr[it];
    float d0 = k4.x * q0.x + k4.y * q0.y + k4.z * q0.z + k4.w * q0.w;
    float d1 = k4.x * q1.x + k4.y * q1.y + k4.z * q1.z + k4.w * q1.w;
    #pragma unroll
    for (int m = 1; m <= 8; m <<= 1) { d0 += __shfl_xor(d0, m); d1 += __shfl_xor(d1, m); }
    if (c == 0) {
      bool valid = (sp <= pos);
      sc0[row] = valid ? d0 * SCALE_ : -1e30f;
      sc1[row] = valid ? d1 * SCALE_ : -1e30f;
    }
  }
  __syncthreads();
  // chunk softmax
  float v0 = (t < 64) ? sc0[t] : -1e30f;
  float v1 = (t < 64) ? sc1[t] : -1e30f;
  float m0 = wave_max(v0), m1 = wave_max(v1);
  if (lane == 0) { red[w] = m0; red[4 + w] = m1; }
  __syncthreads();
  m0 = fmaxf(fmaxf(red[0], red[1]), fmaxf(red[2], red[3]));
  m1 = fmaxf(fmaxf(red[4], red[5]), fmaxf(red[6], red[7]));
  float e0 = (t < 64) ? expf(v0 - m0) : 0.f;
  float e1 = (t < 64) ? expf(v1 - m1) : 0.f;
  __syncthreads();
  if (t < 64) { sc0[t] = e0; sc1[t] = e1; }
  float se0 = wave_sum(e0), se1 = wave_sum(e1);
  if (lane == 0) { red[w] = se0; red[4 + w] = se1; }
  __syncthreads();
  if (t == 0) {
    int base = ((b * HKV_ + kv) * 2) * NCH_ + ns;
    ws[WS_AM + base] = m0;          ws[WS_AM + base + NCH_] = m1;
    ws[WS_AL + base] = red[0] + red[1] + red[2] + red[3];
    ws[WS_AL + base + NCH_] = red[4] + red[5] + red[6] + red[7];
  }
  // PV from registers
  float4 a0 = make_float4(0.f, 0.f, 0.f, 0.f);
  float4 a1 = make_float4(0.f, 0.f, 0.f, 0.f);
  #pragma unroll
  for (int it = 0; it < 4; ++it) {
    int row = it * 16 + w * 4 + r;
    int sp = s0 + row;
    float4 v4 = (sp == pos) ? *(float4*)&vnL[4 * c] : vr[it];
    float p0 = sc0[row], p1 = sc1[row];
    a0.x += p0 * v4.x; a0.y += p0 * v4.y; a0.z += p0 * v4.z; a0.w += p0 * v4.w;
    a1.x += p1 * v4.x; a1.y += p1 * v4.y; a1.z += p1 * v4.z; a1.w += p1 * v4.w;
  }
  #pragma unroll
  for (int m = 16; m <= 32; m <<= 1) {
    a0.x += __shfl_xor(a0.x, m); a0.y += __shfl_xor(a0.y, m);
    a0.z += __shfl_xor(a0.z, m); a0.w += __shfl_xor(a0.w, m);
    a1.x += __shfl_xor(a1.x, m); a1.y += __shfl_xor(a1.y, m);
    a1.z += __shfl_xor(a1.z, m); a1.w += __shfl_xor(a1.w, m);
  }
  if (r == 0) {
    *(float4*)&oacc[0][w][4 * c] = a0;
    *(float4*)&oacc[1][w][4 * c] = a1;
  }
  __syncthreads();
  if (t < 64) {
    float r0 = oacc[0][0][t] + oacc[0][1][t] + oacc[0][2][t] + oacc[0][3][t];
    float r1 = oacc[1][0][t] + oacc[1][1][t] + oacc[1][2][t] + oacc[1][3][t];
    int h0 = kv * 2;
    ws[WS_AO + ((size_t)(b * H_ + h0)     * NCH_ + ns) * 64 + t] = r0;
    ws[WS_AO + ((size_t)(b * H_ + h0 + 1) * NCH_ + ns) * 64 + t] = r1;
  }
}

// ================= K3: o-proj GEMV, atomicAdd residual into HC; zero QA ======
// grid 128 = 4 cb x 32 kc (32 rows each)
__global__ void __launch_bounds__(256)
k3_oproj(const float* __restrict__ Wo, float* __restrict__ ws, int l) {
  int cb = blockIdx.x & 3, kc = blockIdx.x >> 2;
  int t = threadIdx.x;
  int col = cb * 256 + t;
  const float* wp = Wo + ((size_t)l * HID_ + kc * 32) * HID_ + col;
  float wv[32];
  #pragma unroll
  for (int i = 0; i < 32; ++i) wv[i] = wp[(size_t)i * HID_];    // in flight

  if (blockIdx.x < 32) {       // zero QA (8192 floats) for next layer's k1
    ws[WS_QA + blockIdx.x * 256 + t] = 0.f;
  }

  __shared__ __align__(16) float oT[32][4];
  if (t < 128) {
    int bb = t >> 5, jj = t & 31;
    int dim = kc * 32 + jj, h = dim >> 6, d = dim & 63;
    int mb = ((bb * HKV_ + (h >> 1)) * 2 + (h & 1)) * NCH_;
    float mx = -1e30f;
    #pragma unroll
    for (int n = 0; n < NCH_; ++n) mx = fmaxf(mx, ws[WS_AM + mb + n]);
    float ls = 0.f, os = 0.f;
    #pragma unroll
    for (int n = 0; n < NCH_; ++n) {
      float wg = expf(ws[WS_AM + mb + n] - mx);
      ls += wg * ws[WS_AL + mb + n];
      os += wg * ws[WS_AO + ((size_t)(bb * H_ + h) * NCH_ + n) * 64 + d];
    }
    oT[jj][bb] = os / ls;
  }
  __syncthreads();
  float a0 = 0.f, a1 = 0.f, a2 = 0.f, a3 = 0.f;
  #pragma unroll
  for (int i = 0; i < 32; ++i) {
    float w_ = wv[i];
    float4 o4 = *(float4*)&oT[i][0];
    a0 += w_ * o4.x; a1 += w_ * o4.y; a2 += w_ * o4.z; a3 += w_ * o4.w;
  }
  atomicAdd(ws + WS_HC + 0 * HID_ + col, MUP_ * a0);
  atomicAdd(ws + WS_HC + 1 * HID_ + col, MUP_ * a1);
  atomicAdd(ws + WS_HC + 2 * HID_ + col, MUP_ * a2);
  atomicAdd(ws + WS_HC + 3 * HID_ + col, MUP_ * a3);
}

// ================= K4: gate/up GEMV (RMS on HC) -> atomicAdd GA/UA ===========
// grid 352 = 11 cb x 32 kc (32 rows each)
__global__ void __launch_bounds__(256)
k4_gateup(const float* __restrict__ Wg, const float* __restrict__ Wu,
          const float* __restrict__ n2, float* __restrict__ ws, int l) {
  int cb = blockIdx.x % 11, kc = blockIdx.x / 11;
  int t = threadIdx.x;
  int col = cb * 256 + t;
  const float* wgp = Wg + ((size_t)l * HID_ + kc * 32) * FF_ + col;
  const float* wup = Wu + ((size_t)l * HID_ + kc * 32) * FF_ + col;
  float gv[32], uv[32];
  #pragma unroll
  for (int i = 0; i < 32; ++i) { gv[i] = wgp[(size_t)i * FF_]; uv[i] = wup[(size_t)i * FF_]; }

  const float* hsrc = ws + WS_HC;
  __shared__ float red[16];
  __shared__ __align__(16) float xs[4][32];
  float rs[4];
  rms_of(hsrc, red, rs);
  if (t < 128) {
    int b = t >> 5, i = t & 31;
    int gc = kc * 32 + i;
    xs[b][i] = hsrc[b * HID_ + gc] * rs[b] * n2[l * HID_ + gc];
  }
  __syncthreads();
  float g0 = 0.f, g1 = 0.f, g2 = 0.f, g3 = 0.f;
  float u0 = 0.f, u1 = 0.f, u2 = 0.f, u3 = 0.f;
  #pragma unroll
  for (int i = 0; i < 32; ++i) {
    float g = gv[i], u = uv[i];
    float x0 = xs[0][i], x1 = xs[1][i], x2 = xs[2][i], x3 = xs[3][i];
    g0 += g * x0; g1 += g * x1; g2 += g * x2; g3 += g * x3;
    u0 += u * x0; u1 += u * x1; u2 += u * x2; u3 += u * x3;
  }
  atomicAdd(ws + WS_GA + 0 * FF_ + col, g0);
  atomicAdd(ws + WS_GA + 1 * FF_ + col, g1);
  atomicAdd(ws + WS_GA + 2 * FF_ + col, g2);
  atomicAdd(ws + WS_GA + 3 * FF_ + col, g3);
  atomicAdd(ws + WS_UA + 0 * FF_ + col, u0);
  atomicAdd(ws + WS_UA + 1 * FF_ + col, u1);
  atomicAdd(ws + WS_UA + 2 * FF_ + col, u2);
  atomicAdd(ws + WS_UA + 3 * FF_ + col, u3);
}

// ================= K5: down GEMV (silu from GA/UA), atomicAdd into HC ========
// grid 176 = 4 cb x 44 kc (64 rows each)
__global__ void __launch_bounds__(256)
k5_down(const float* __restrict__ Wd, float* __restrict__ ws, int l) {
  int cb = blockIdx.x & 3, kc = blockIdx.x >> 2;   // kc<44
  int t = threadIdx.x;
  int col = cb * 256 + t;
  const float* wp = Wd + ((size_t)l * FF_ + kc * 64) * HID_ + col;
  float wv[64];
  #pragma unroll
  for (int i = 0; i < 64; ++i) wv[i] = wp[(size_t)i * HID_];    // in flight

  __shared__ __align__(16) float mT[64][4];
  {
    int bb = t >> 6, jj = t & 63;       // 256 items = 64 rows x 4 batches
    int f = kc * 64 + jj;
    float g = ws[WS_GA + bb * FF_ + f];
    float u = ws[WS_UA + bb * FF_ + f];
    float sig = 1.f / (1.f + expf(-g));
    mT[jj][bb] = g * sig * u;
  }
  __syncthreads();
  float a0 = 0.f, a1 = 0.f, a2 = 0.f, a3 = 0.f;
  #pragma unroll
  for (int i = 0; i < 64; ++i) {
    float w_ = wv[i];
    float4 m4 = *(float4*)&mT[i][0];
    a0 += w_ * m4.x; a1 += w_ * m4.y; a2 += w_ * m4.z; a3 += w_ * m4.w;
  }
  atomicAdd(ws + WS_HC + 0 * HID_ + col, MUP_ * a0);
  atomicAdd(ws + WS_HC + 1 * HID_ + col, MUP_ * a1);
  atomicAdd(ws + WS_HC + 2 * HID_ + col, MUP_ * a2);
  atomicAdd(ws + WS_HC + 3 * HID_ + col, MUP_ * a3);
}

// ================= K6: final RMS(HC)*fw -> out, plus pos+1 ===================
__global__ void __launch_bounds__(256)
k6_final(const float* __restrict__ fw, const int* __restrict__ posp,
         float* __restrict__ ws, float* __restrict__ out) {
  int b = blockIdx.x, t = threadIdx.x;
  __shared__ float red[4];
  float hv[4];
  float part = 0.f;
  for (int j = 0; j < 4; ++j) {
    float v = ws[WS_HC + b * HID_ + t + j * 256];
    hv[j] = v; part += v * v;
  }
  part = wave_sum(part);
  if ((t & 63) == 0) red[t >> 6] = part;
  __syncthreads();
  float rs = rsqrtf((red[0] + red[1] + red[2] + red[3]) * (1.0f / HID_) + EPS_);
  for (int j = 0; j < 4; ++j) {
    int c2 = t + j * 256;
    out[OUT_H + b * HID_ + c2] = hv[j] * rs * fw[c2];
  }
  if (b == 0 && t == 0) out[OUT_POS] = (float)(read_pos_dev(posp) + 1);
}

extern "C" void kernel_launch(void* const* d_in, const int* in_sizes, int n_in,
                              void* d_out, int out_size, void* d_ws, size_t ws_size,
                              hipStream_t stream) {
  const float* x   = (const float*)d_in[0];
  const float* kcp = (const float*)d_in[1];
  const float* vcp = (const float*)d_in[2];
  const float* Wq  = (const float*)d_in[3];
  const float* Wk  = (const float*)d_in[4];
  const float* Wv  = (const float*)d_in[5];
  const float* Wo  = (const float*)d_in[6];
  const float* Wg  = (const float*)d_in[7];
  const float* Wu  = (const float*)d_in[8];
  const float* Wd  = (const float*)d_in[9];
  const float* n1  = (const float*)d_in[10];
  const float* n2  = (const float*)d_in[11];
  const float* fw  = (const float*)d_in[12];
  const int*   pos = (const int*)d_in[13];
  float* ws  = (float*)d_ws;
  float* out = (float*)d_out;

  // seed QA = 0 for layer 0 (k3 re-zeroes it each layer thereafter)
  hipMemsetAsync(ws + WS_QA, 0, 8192 * sizeof(float), stream);

  for (int l = 0; l < L_; ++l) {
    k1_qkv   <<< 256, 256, 0, stream>>>(Wq, Wk, Wv, n1, x, ws, l);
    k2_attn  <<<1024, 256, 0, stream>>>(kcp, vcp, pos, ws, out, l);
    k3_oproj <<< 128, 256, 0, stream>>>(Wo, ws, l);
    k4_gateup<<< 352, 256, 0, stream>>>(Wg, Wu, n2, ws, l);
    k5_down  <<< 176, 256, 0, stream>>>(Wd, ws, l);
  }
  k6_final<<<4, 256, 0, stream>>>(fw, pos, ws, out);
}